// Round 11
// baseline (391.727 us; speedup 1.0000x reference)
//
#include <hip/hip_runtime.h>

// Problem constants (setup_inputs: B=2, C=256, H=W=48, p=3)
constexpr int B_  = 2;
constexpr int C_  = 256;
constexpr int H_  = 48;
constexpr int W_  = 48;
constexpr int N_  = H_ * W_;          // 2304
constexpr int PH_ = H_ + 2;           // 50
constexpr int PW_ = W_ + 2;           // 50
constexpr int NP_ = PH_ * PW_;        // 2500
constexpr int NPS_ = 2560;            // k-major row stride
constexpr int MS_  = 2560;            // M row stride (padded)
constexpr int CC_ = C_ * C_;          // 65536
constexpr int NCH_ = 36;              // n-chunks for score partial argmax
constexpr int NC_  = N_ / NCH_;       // 64
constexpr int NSIT_ = 5;              // Newton-Schulz iterations (e5 ~ 5e-10)
constexpr int KCH_ = 9;               // cov K-chunks (2304 = 9*256)

// ---------------- reduction helpers ----------------
__device__ inline float waveRed(float v) {
  #pragma unroll
  for (int o = 32; o > 0; o >>= 1) v += __shfl_down(v, o);
  return v;
}

// 16-FMA inner step on staged 64-wide tiles
#define GEMM64_COMPUTE(sAT, sB, acc, ty, tx)                        \
  _Pragma("unroll")                                                 \
  for (int kk = 0; kk < 16; kk++) {                                 \
    float4 a = *(const float4*)&sAT[kk][(ty) * 4];                  \
    float4 b = *(const float4*)&sB[kk][(tx) * 4];                   \
    acc[0][0] += a.x * b.x; acc[0][1] += a.x * b.y;                 \
    acc[0][2] += a.x * b.z; acc[0][3] += a.x * b.w;                 \
    acc[1][0] += a.y * b.x; acc[1][1] += a.y * b.y;                 \
    acc[1][2] += a.y * b.z; acc[1][3] += a.y * b.w;                 \
    acc[2][0] += a.z * b.x; acc[2][1] += a.z * b.y;                 \
    acc[2][2] += a.z * b.z; acc[2][3] += a.z * b.w;                 \
    acc[3][0] += a.w * b.x; acc[3][1] += a.w * b.y;                 \
    acc[3][2] += a.w * b.z; acc[3][3] += a.w * b.w;                 \
  }

// ---------------- kernels ----------------

// Per-(b,c) mean over N, write centered rows. which=0: content->fc, 1: style->fs
__global__ __launch_bounds__(256) void center_kernel(
    const float* __restrict__ content, const float* __restrict__ style,
    float* __restrict__ fc, float* __restrict__ fs, float* __restrict__ mean_s) {
  int t = blockIdx.x;
  int which = t / (B_ * C_);
  int bc = t % (B_ * C_);
  const float* src = which ? style : content;
  float* dst = which ? fs : fc;
  const float* row = src + (size_t)bc * N_;
  float acc = 0.f;
  for (int i = threadIdx.x; i < N_; i += 256) acc += row[i];
  __shared__ float sm[4];
  float r = waveRed(acc);
  if ((threadIdx.x & 63) == 0) sm[threadIdx.x >> 6] = r;
  __syncthreads();
  float mean = (sm[0] + sm[1] + sm[2] + sm[3]) * (1.0f / N_);
  for (int i = threadIdx.x; i < N_; i += 256) dst[(size_t)bc * N_ + i] = row[i] - mean;
  if (which == 1 && threadIdx.x == 0) mean_s[bc] = mean;
}

// K-split covariance partials: z = ci*4+m. 64x64 tile, both operands transposed-staged.
__global__ __launch_bounds__(256) void cov_kernel(
    const float* __restrict__ fc, const float* __restrict__ fs, float* __restrict__ pcov) {
  int z = blockIdx.z;
  int m = z & 3, ci = z >> 2;
  const float* f = (m < 2) ? (fc + (size_t)m * C_ * N_) : (fs + (size_t)(m - 2) * C_ * N_);
  int i0 = blockIdx.y * 64, j0 = blockIdx.x * 64;
  int t = threadIdx.x;
  int tx = t & 15, ty = t >> 4;
  int sr = t >> 2, skq = t & 3;
  __shared__ float sAT[16][68], sB[16][68];
  float acc[4][4] = {};
  int k0e = ci * 256 + 256;
  for (int k0 = ci * 256; k0 < k0e; k0 += 16) {
    float4 av = *(const float4*)&f[(size_t)(i0 + sr) * N_ + k0 + skq * 4];
    float4 bv = *(const float4*)&f[(size_t)(j0 + sr) * N_ + k0 + skq * 4];
    __syncthreads();
    sAT[skq * 4 + 0][sr] = av.x; sAT[skq * 4 + 1][sr] = av.y;
    sAT[skq * 4 + 2][sr] = av.z; sAT[skq * 4 + 3][sr] = av.w;
    sB[skq * 4 + 0][sr] = bv.x;  sB[skq * 4 + 1][sr] = bv.y;
    sB[skq * 4 + 2][sr] = bv.z;  sB[skq * 4 + 3][sr] = bv.w;
    __syncthreads();
    GEMM64_COMPUTE(sAT, sB, acc, ty, tx)
  }
  float* out = pcov + ((size_t)ci * 4 + m) * CC_;
  for (int u = 0; u < 4; u++)
    for (int v = 0; v < 4; v++)
      out[(size_t)(i0 + ty * 4 + u) * C_ + (j0 + tx * 4 + v)] = acc[u][v];
}

// A4[m] = (sum_ci pcov[ci][m]) / (N-1)
__global__ __launch_bounds__(256) void covreduce(
    const float* __restrict__ pcov, float* __restrict__ A4) {
  int t = blockIdx.x * 256 + threadIdx.x;
  float acc = 0.f;
  #pragma unroll
  for (int ci = 0; ci < KCH_; ci++) acc += pcov[(size_t)ci * 4 * CC_ + t];
  A4[t] = acc * (1.0f / (float)(N_ - 1));
}

// 2-partial init: Yp[p0]=A/s, Yp[p1]=0; Zp[p0]=I, Zp[p1]=0. grid (16,4)
__global__ __launch_bounds__(256) void ns_init(
    const float* __restrict__ A4, float* __restrict__ Yp, float* __restrict__ Zp,
    float* __restrict__ scal) {
  int m = blockIdx.y, s = blockIdx.x;
  const float* A = A4 + (size_t)m * CC_;
  float d = A[(size_t)threadIdx.x * 257];
  __shared__ float sm[4];
  float r = waveRed(d);
  if ((threadIdx.x & 63) == 0) sm[threadIdx.x >> 6] = r;
  __syncthreads();
  float trace = sm[0] + sm[1] + sm[2] + sm[3];
  float sc = 1.1f * trace / (float)C_;
  if (s == 0 && threadIdx.x == 0) scal[m] = sc;
  float inv = 1.0f / sc;
  int i0 = s * (CC_ / 16);
  for (int i = i0 + threadIdx.x; i < i0 + CC_ / 16; i += 256) {
    Yp[(size_t)m * CC_ + i] = A[i] * inv;
    Zp[(size_t)m * CC_ + i] = ((i >> 8) == (i & 255)) ? 1.0f : 0.0f;
    Yp[(size_t)(4 + m) * CC_ + i] = 0.f;
    Zp[(size_t)(4 + m) * CC_ + i] = 0.f;
  }
}

// T_kh = (kh==0?3I:0) - (Zp0+Zp1)(Yp0+Yp1) over K in [kh*128,(kh+1)*128).
// 32x32 tiles, BK=32. grid (8,8,8): z = kh*4+m
__global__ __launch_bounds__(256) void ns_stepA(
    const float* __restrict__ Zp, const float* __restrict__ Yp, float* __restrict__ Tp) {
  int z = blockIdx.z;
  int m = z & 3, kh = z >> 2;
  const float* A0 = Zp + (size_t)m * CC_;
  const float* A1 = Zp + (size_t)(4 + m) * CC_;
  const float* B0 = Yp + (size_t)m * CC_;
  const float* B1 = Yp + (size_t)(4 + m) * CC_;
  float* out = Tp + (size_t)(kh * 4 + m) * CC_;
  int i0 = blockIdx.y * 32, j0 = blockIdx.x * 32;
  int t = threadIdx.x;
  int tx = t & 15, ty = t >> 4;
  int sr = t >> 3, sc4 = t & 7;
  __shared__ float sAT[32][36], sB[32][36];
  float acc[2][2] = {};
  int k0e = kh * 128 + 128;
  for (int k0 = kh * 128; k0 < k0e; k0 += 32) {
    size_t ia = (size_t)(i0 + sr) * 256 + k0 + sc4 * 4;
    size_t ib = (size_t)(k0 + sr) * 256 + j0 + sc4 * 4;
    float4 a0 = *(const float4*)&A0[ia];
    float4 a1 = *(const float4*)&A1[ia];
    float4 b0 = *(const float4*)&B0[ib];
    float4 b1 = *(const float4*)&B1[ib];
    float4 av = {a0.x + a1.x, a0.y + a1.y, a0.z + a1.z, a0.w + a1.w};
    float4 bv = {b0.x + b1.x, b0.y + b1.y, b0.z + b1.z, b0.w + b1.w};
    __syncthreads();
    sAT[sc4 * 4 + 0][sr] = av.x; sAT[sc4 * 4 + 1][sr] = av.y;
    sAT[sc4 * 4 + 2][sr] = av.z; sAT[sc4 * 4 + 3][sr] = av.w;
    *(float4*)&sB[sr][sc4 * 4] = bv;
    __syncthreads();
    #pragma unroll
    for (int kk = 0; kk < 32; kk++) {
      float2 a = *(const float2*)&sAT[kk][ty * 2];
      float2 b = *(const float2*)&sB[kk][tx * 2];
      acc[0][0] += a.x * b.x; acc[0][1] += a.x * b.y;
      acc[1][0] += a.y * b.x; acc[1][1] += a.y * b.y;
    }
    __syncthreads();
  }
  for (int u = 0; u < 2; u++)
    for (int v = 0; v < 2; v++) {
      int i = i0 + ty * 2 + u, j = j0 + tx * 2 + v;
      float d = (kh == 0 && i == j) ? 3.0f : 0.0f;
      out[(size_t)i * 256 + j] = d - acc[u][v];
    }
}

// grid (8,8,16): m=z&3, kh=(z>>2)&1, doY=z<8. Yn_kh=0.5*Y*T | Zn_kh=0.5*T*Z (K-restricted)
__global__ __launch_bounds__(256) void ns_stepB(
    const float* __restrict__ Yp, const float* __restrict__ Zp, const float* __restrict__ Tp,
    float* __restrict__ Ynp, float* __restrict__ Znp) {
  int z = blockIdx.z;
  int m = z & 3, kh = (z >> 2) & 1;
  bool doY = (z < 8);
  const float* A0 = (doY ? Yp : Tp) + (size_t)m * CC_;
  const float* A1 = (doY ? Yp : Tp) + (size_t)(4 + m) * CC_;
  const float* B0 = (doY ? Tp : Zp) + (size_t)m * CC_;
  const float* B1 = (doY ? Tp : Zp) + (size_t)(4 + m) * CC_;
  float* out = (doY ? Ynp : Znp) + (size_t)(kh * 4 + m) * CC_;
  int i0 = blockIdx.y * 32, j0 = blockIdx.x * 32;
  int t = threadIdx.x;
  int tx = t & 15, ty = t >> 4;
  int sr = t >> 3, sc4 = t & 7;
  __shared__ float sAT[32][36], sB[32][36];
  float acc[2][2] = {};
  int k0e = kh * 128 + 128;
  for (int k0 = kh * 128; k0 < k0e; k0 += 32) {
    size_t ia = (size_t)(i0 + sr) * 256 + k0 + sc4 * 4;
    size_t ib = (size_t)(k0 + sr) * 256 + j0 + sc4 * 4;
    float4 a0 = *(const float4*)&A0[ia];
    float4 a1 = *(const float4*)&A1[ia];
    float4 b0 = *(const float4*)&B0[ib];
    float4 b1 = *(const float4*)&B1[ib];
    float4 av = {a0.x + a1.x, a0.y + a1.y, a0.z + a1.z, a0.w + a1.w};
    float4 bv = {b0.x + b1.x, b0.y + b1.y, b0.z + b1.z, b0.w + b1.w};
    __syncthreads();
    sAT[sc4 * 4 + 0][sr] = av.x; sAT[sc4 * 4 + 1][sr] = av.y;
    sAT[sc4 * 4 + 2][sr] = av.z; sAT[sc4 * 4 + 3][sr] = av.w;
    *(float4*)&sB[sr][sc4 * 4] = bv;
    __syncthreads();
    #pragma unroll
    for (int kk = 0; kk < 32; kk++) {
      float2 a = *(const float2*)&sAT[kk][ty * 2];
      float2 b = *(const float2*)&sB[kk][tx * 2];
      acc[0][0] += a.x * b.x; acc[0][1] += a.x * b.y;
      acc[1][0] += a.y * b.x; acc[1][1] += a.y * b.y;
    }
    __syncthreads();
  }
  for (int u = 0; u < 2; u++)
    for (int v = 0; v < 2; v++) {
      int i = i0 + ty * 2 + u, j = j0 + tx * 2 + v;
      out[(size_t)i * 256 + j] = 0.5f * acc[u][v];
    }
}

// (Zp0+Zp1)/sqrt(s) * f -> padded buffers. m<2: content -> ncP [b][c][NPS] (k-major);
// m>=2: style -> nsP [b][NP][c] AND nsT [b][c][NPS] (k-major).  grid (36,4,4)
__global__ __launch_bounds__(256) void whiten_pad(
    const float* __restrict__ Zf, const float* __restrict__ scal,
    const float* __restrict__ fc, const float* __restrict__ fs,
    float* __restrict__ ncP, float* __restrict__ nsP, float* __restrict__ nsT) {
  int m = blockIdx.z;
  const float* f = (m < 2) ? (fc + (size_t)m * C_ * N_) : (fs + (size_t)(m - 2) * C_ * N_);
  int c0 = blockIdx.y * 64, x0 = blockIdx.x * 64;
  int t = threadIdx.x;
  int tx = t & 15, ty = t >> 4;
  int sr = t >> 2, skq = t & 3;
  int bkk = t & 15, bc4 = t >> 4;
  __shared__ float sAT[16][68], sB[16][68];
  float acc[4][4] = {};
  for (int k0 = 0; k0 < 256; k0 += 16) {
    size_t ia = (size_t)(c0 + sr) * 256 + k0 + skq * 4;
    float4 a0 = *(const float4*)&Zf[(size_t)m * CC_ + ia];
    float4 a1 = *(const float4*)&Zf[(size_t)(4 + m) * CC_ + ia];
    float4 av = {a0.x + a1.x, a0.y + a1.y, a0.z + a1.z, a0.w + a1.w};
    float4 bv = *(const float4*)&f[(size_t)(k0 + bkk) * N_ + x0 + bc4 * 4];
    __syncthreads();
    sAT[skq * 4 + 0][sr] = av.x; sAT[skq * 4 + 1][sr] = av.y;
    sAT[skq * 4 + 2][sr] = av.z; sAT[skq * 4 + 3][sr] = av.w;
    *(float4*)&sB[bkk][bc4 * 4] = bv;
    __syncthreads();
    GEMM64_COMPUTE(sAT, sB, acc, ty, tx)
  }
  float rs = rsqrtf(scal[m]);
  int b = (m < 2) ? m : (m - 2);
  for (int u = 0; u < 4; u++)
    for (int v = 0; v < 4; v++) {
      int c = c0 + ty * 4 + u, x = x0 + tx * 4 + v;
      int h = x / W_, w = x % W_;
      int pp = (h + 1) * PW_ + (w + 1);
      float val = acc[u][v] * rs;
      if (m < 2) {
        ncP[((size_t)b * C_ + c) * NPS_ + pp] = val;
      } else {
        nsP[((size_t)b * NP_ + pp) * C_ + c] = val;
        nsT[((size_t)b * C_ + c) * NPS_ + pp] = val;
      }
    }
}

// q[b][p] = sum_c nsP[b][p][c]^2
__global__ __launch_bounds__(256) void q_kernel(const float* __restrict__ nsP, float* __restrict__ q) {
  int wid = (blockIdx.x * 256 + threadIdx.x) >> 6;
  int lane = threadIdx.x & 63;
  if (wid >= B_ * NP_) return;
  const float* v = nsP + (size_t)wid * C_;
  float acc = 0.f;
  #pragma unroll
  for (int c = lane; c < C_; c += 64) { float t = v[c]; acc += t * t; }
  acc = waveRed(acc);
  if (lane == 0) q[wid] = acc;
}

// kninv[b][n] = rsqrt( sum over 3x3 of q )
__global__ __launch_bounds__(256) void kninv_kernel(const float* __restrict__ q, float* __restrict__ kninv) {
  int t = blockIdx.x * 256 + threadIdx.x;
  if (t >= B_ * N_) return;
  int b = t / N_, n = t % N_;
  int hn = n / W_, wn = n % W_;
  const float* qb = q + (size_t)b * NP_ + hn * PW_ + wn;
  float s = 0.f;
  #pragma unroll
  for (int i = 0; i < 3; i++)
    #pragma unroll
    for (int j = 0; j < 3; j++) s += qb[i * PW_ + j];
  kninv[t] = rsqrtf(s);
}

// M[i][j] = sum_k At[k][i]*Bt[k][j]; both k-major (stride NPS_), M padded stride MS_.
// v3: 128x128 tile, BK=32, acc[8][8], unpadded LDS rows (conflict-free: reads are
// broadcast or 2-way). grid (20, 20, z). blockIdx.z = batch.
__global__ __launch_bounds__(256) void m_kernel(
    const float* __restrict__ At, const float* __restrict__ Bt, float* __restrict__ M,
    size_t batchA, size_t batchM) {
  size_t bz = blockIdx.z;
  At += bz * batchA; Bt += bz * batchA; M += bz * batchM;
  int i0 = blockIdx.y * 128, j0 = blockIdx.x * 128;
  int t = threadIdx.x;
  int tx = t & 15, ty = t >> 4;
  __shared__ float sA[32][128], sB[32][128];
  float acc[8][8] = {};
  for (int k0 = 0; k0 < 256; k0 += 32) {
    float4 a[4], b[4];
    #pragma unroll
    for (int r = 0; r < 4; r++) {
      int s = r * 256 + t, kk = s >> 5, c4 = s & 31;
      a[r] = *(const float4*)&At[(size_t)(k0 + kk) * NPS_ + i0 + c4 * 4];
      b[r] = *(const float4*)&Bt[(size_t)(k0 + kk) * NPS_ + j0 + c4 * 4];
    }
    __syncthreads();
    #pragma unroll
    for (int r = 0; r < 4; r++) {
      int s = r * 256 + t, kk = s >> 5, c4 = s & 31;
      *(float4*)&sA[kk][c4 * 4] = a[r];
      *(float4*)&sB[kk][c4 * 4] = b[r];
    }
    __syncthreads();
    #pragma unroll
    for (int kk = 0; kk < 32; kk++) {
      float4 aL = *(const float4*)&sA[kk][ty * 4];
      float4 aH = *(const float4*)&sA[kk][64 + ty * 4];
      float4 bL = *(const float4*)&sB[kk][tx * 4];
      float4 bH = *(const float4*)&sB[kk][64 + tx * 4];
      float av[8] = {aL.x, aL.y, aL.z, aL.w, aH.x, aH.y, aH.z, aH.w};
      float bv[8] = {bL.x, bL.y, bL.z, bL.w, bH.x, bH.y, bH.z, bH.w};
      #pragma unroll
      for (int u = 0; u < 8; u++)
        #pragma unroll
        for (int v = 0; v < 8; v++)
          acc[u][v] += av[u] * bv[v];
    }
    __syncthreads();
  }
  #pragma unroll
  for (int u = 0; u < 8; u++) {
    int row = i0 + ((u < 4) ? (ty * 4 + u) : (64 + ty * 4 + (u - 4)));
    float4 s0 = {acc[u][0], acc[u][1], acc[u][2], acc[u][3]};
    float4 s1 = {acc[u][4], acc[u][5], acc[u][6], acc[u][7]};
    *(float4*)&M[(size_t)row * MS_ + j0 + tx * 4] = s0;
    *(float4*)&M[(size_t)row * MS_ + j0 + 64 + tx * 4] = s1;
  }
}

// Partial argmax over an n-chunk for each content position m. (M stride MS_)
// batch = b0 + blockIdx.z; M offset by blockIdx.z * batchM.
__global__ __launch_bounds__(256) void score_kernel(
    const float* __restrict__ M, const float* __restrict__ kninv,
    float* __restrict__ pval, int* __restrict__ pidx, int b0, size_t batchM) {
  int b = b0 + blockIdx.z;
  M += (size_t)blockIdx.z * batchM;
  int m = blockIdx.x * 256 + threadIdx.x;
  int h = m / W_, w = m % W_;
  int cm = h * PW_ + w;
  int n0 = blockIdx.y * NC_;
  const float* kni = kninv + (size_t)b * N_;
  float best = -3.4e38f;
  int bidx = n0;
  for (int n = n0; n < n0 + NC_; n++) {
    int hn = n / W_, wn = n % W_;
    int rn = hn * PW_ + wn;
    const float* base = M + (size_t)rn * MS_ + cm;
    float s = 0.f;
    #pragma unroll
    for (int i = 0; i < 3; i++)
      #pragma unroll
      for (int j = 0; j < 3; j++) s += base[(size_t)(i * PW_ + j) * (MS_ + 1)];
    s *= kni[n];
    if (s > best) { best = s; bidx = n; }
  }
  pval[((size_t)b * NCH_ + blockIdx.y) * N_ + m] = best;
  pidx[((size_t)b * NCH_ + blockIdx.y) * N_ + m] = bidx;
}

// Final argmax across chunks (ascending => first-max wins, matches jnp.argmax)
__global__ __launch_bounds__(256) void argmax_final(
    const float* __restrict__ pval, const int* __restrict__ pidx, int* __restrict__ idxb) {
  int t = blockIdx.x * 256 + threadIdx.x;
  if (t >= B_ * N_) return;
  int b = t / N_, m = t % N_;
  float best = -3.4e38f; int bidx = 0;
  for (int ch = 0; ch < NCH_; ch++) {
    float v = pval[((size_t)b * NCH_ + ch) * N_ + m];
    int i = pidx[((size_t)b * NCH_ + ch) * N_ + m];
    if (v > best) { best = v; bidx = i; }
  }
  idxb[t] = bidx;
}

// Overlap-add reassembly: recon[b][m][c] (position-major)
__global__ __launch_bounds__(256) void reassemble_kernel(
    const float* __restrict__ nsP, const int* __restrict__ idxb, float* __restrict__ recon) {
  int bm = blockIdx.x;
  int b = bm / N_, m = bm % N_;
  int h = m / W_, w = m % W_;
  int c = threadIdx.x;
  float acc = 0.f; int cnt = 0;
  for (int di = 0; di < 3; di++) {
    int hs = h + 1 - di; if (hs < 0 || hs >= H_) continue;
    for (int dj = 0; dj < 3; dj++) {
      int ws = w + 1 - dj; if (ws < 0 || ws >= W_) continue;
      int n = idxb[(size_t)b * N_ + hs * W_ + ws];
      int hn = n / W_, wn = n % W_;
      int pp = (hn + di) * PW_ + (wn + dj);
      acc += nsP[((size_t)b * NP_ + pp) * C_ + c];
      cnt++;
    }
  }
  recon[((size_t)b * N_ + m) * C_ + c] = acc / (float)cnt;
}

// Partial column sums of recon over x-chunks
__global__ __launch_bounds__(256) void rmean_part(const float* __restrict__ recon, float* __restrict__ pmr) {
  int b = blockIdx.y, ch = blockIdx.x, c = threadIdx.x;
  float acc = 0.f;
  int x0 = ch * (N_ / 16);
  for (int x = x0; x < x0 + (N_ / 16); x++) acc += recon[((size_t)b * N_ + x) * C_ + c];
  pmr[((size_t)b * 16 + ch) * C_ + c] = acc;
}

__global__ __launch_bounds__(256) void rmean_fin(const float* __restrict__ pmr, float* __restrict__ mr) {
  int b = blockIdx.x, c = threadIdx.x;
  float acc = 0.f;
  for (int ch = 0; ch < 16; ch++) acc += pmr[((size_t)b * 16 + ch) * C_ + c];
  mr[(size_t)b * C_ + c] = acc * (1.0f / N_);
}

// stylized = sqrt(cov_s)*(recon-mr) + mean_s ; out = (1-ss)*content + ss*stylized
// grid (36,4,2). A = (Yp0+Yp1) (style matrix m=2+b)
__global__ __launch_bounds__(256) void color_blend(
    const float* __restrict__ Yf, const float* __restrict__ scal,
    const float* __restrict__ recon, const float* __restrict__ mr,
    const float* __restrict__ msty, const float* __restrict__ content,
    const float* __restrict__ ssp, float* __restrict__ out) {
  int b = blockIdx.z;
  int m = 2 + b;
  int c0 = blockIdx.y * 64, x0 = blockIdx.x * 64;
  int t = threadIdx.x;
  int tx = t & 15, ty = t >> 4;
  int sr = t >> 2, skq = t & 3;
  __shared__ float sAT[16][68], sB[16][68];
  float acc[4][4] = {};
  for (int k0 = 0; k0 < 256; k0 += 16) {
    size_t ia = (size_t)(c0 + sr) * 256 + k0 + skq * 4;
    float4 a0 = *(const float4*)&Yf[(size_t)m * CC_ + ia];
    float4 a1 = *(const float4*)&Yf[(size_t)(4 + m) * CC_ + ia];
    float4 av = {a0.x + a1.x, a0.y + a1.y, a0.z + a1.z, a0.w + a1.w};
    float4 bm4 = *(const float4*)&mr[(size_t)b * C_ + k0 + skq * 4];
    float4 bv = *(const float4*)&recon[((size_t)b * N_ + x0 + sr) * C_ + k0 + skq * 4];
    bv.x -= bm4.x; bv.y -= bm4.y; bv.z -= bm4.z; bv.w -= bm4.w;
    __syncthreads();
    sAT[skq * 4 + 0][sr] = av.x; sAT[skq * 4 + 1][sr] = av.y;
    sAT[skq * 4 + 2][sr] = av.z; sAT[skq * 4 + 3][sr] = av.w;
    sB[skq * 4 + 0][sr] = bv.x;  sB[skq * 4 + 1][sr] = bv.y;
    sB[skq * 4 + 2][sr] = bv.z;  sB[skq * 4 + 3][sr] = bv.w;
    __syncthreads();
    GEMM64_COMPUTE(sAT, sB, acc, ty, tx)
  }
  float sq = sqrtf(scal[m]);
  float ss = ssp[0];
  for (int u = 0; u < 4; u++)
    for (int v = 0; v < 4; v++) {
      int c = c0 + ty * 4 + u, x = x0 + tx * 4 + v;
      float sty = acc[u][v] * sq + msty[(size_t)b * C_ + c];
      size_t o = ((size_t)b * C_ + c) * N_ + x;
      out[o] = (1.0f - ss) * content[o] + ss * sty;
    }
}

// ---------------- host launch ----------------
extern "C" void kernel_launch(void* const* d_in, const int* in_sizes, int n_in,
                              void* d_out, int out_size, void* d_ws, size_t ws_size,
                              hipStream_t stream) {
  (void)in_sizes; (void)n_in; (void)out_size;
  const float* content = (const float*)d_in[0];
  const float* style   = (const float*)d_in[1];
  const float* ssp     = (const float*)d_in[2];
  float* out = (float*)d_out;
  float* W = (float*)d_ws;

  // workspace layout (floats)
  size_t off = 0;
  float* fc   = W + off; off += (size_t)B_ * C_ * N_;
  float* fs   = W + off; off += (size_t)B_ * C_ * N_;   // recon aliases fs later
  float* nsP  = W + off; off += (size_t)B_ * NP_ * C_;
  float* nsT  = W + off; off += (size_t)B_ * C_ * NPS_;
  float* ncP  = W + off; off += (size_t)B_ * C_ * NPS_;
  float* A4   = W + off; off += (size_t)4 * CC_;
  float* Ya   = W + off; off += (size_t)8 * CC_;   // 2-partial sets
  float* Yb   = W + off; off += (size_t)8 * CC_;
  float* Za   = W + off; off += (size_t)8 * CC_;
  float* Zb   = W + off; off += (size_t)8 * CC_;
  float* scal = W + off; off += 4;
  float* msty = W + off; off += (size_t)B_ * C_;
  float* mr   = W + off; off += (size_t)B_ * C_;
  float* pmr  = W + off; off += (size_t)B_ * 16 * C_;
  float* q    = W + off; off += (size_t)B_ * NP_;
  float* kni  = W + off; off += (size_t)B_ * N_;
  float* pval = W + off; off += (size_t)B_ * NCH_ * N_;
  float* Mb   = W + off;
  size_t off_Mb = off;

  size_t off1 = off_Mb + (size_t)MS_ * MS_;        // single-M layout
  size_t off2 = off_Mb + (size_t)2 * MS_ * MS_;    // dual-M layout
  size_t tail = (size_t)B_ * NCH_ * N_ + (size_t)B_ * N_;   // pidx + idxb
  bool dual = ws_size >= (off2 + tail) * sizeof(float);
  size_t offM = dual ? off2 : off1;
  int* pidx = (int*)(W + offM);
  int* idxb = (int*)(W + offM + (size_t)B_ * NCH_ * N_);
  float* pcov = Mb;          // 9*4*CC = 2.36M floats (dead before m_kernel)
  float* T    = Mb;          // 8*CC floats; used only during NS
  float* recon = fs;         // fs dead after whiten_pad

  hipMemsetAsync(nsP, 0, (size_t)B_ * NP_ * C_ * sizeof(float), stream);
  hipMemsetAsync(nsT, 0, (size_t)B_ * C_ * NPS_ * sizeof(float), stream);
  hipMemsetAsync(ncP, 0, (size_t)B_ * C_ * NPS_ * sizeof(float), stream);

  center_kernel<<<2 * B_ * C_, 256, 0, stream>>>(content, style, fc, fs, msty);
  cov_kernel<<<dim3(4, 4, 4 * KCH_), 256, 0, stream>>>(fc, fs, pcov);
  covreduce<<<4 * CC_ / 256, 256, 0, stream>>>(pcov, A4);
  ns_init<<<dim3(16, 4), 256, 0, stream>>>(A4, Ya, Za, scal);

  float *Ycur = Ya, *Zcur = Za, *Yalt = Yb, *Zalt = Zb;
  for (int it = 0; it < NSIT_; it++) {
    ns_stepA<<<dim3(8, 8, 8), 256, 0, stream>>>(Zcur, Ycur, T);
    ns_stepB<<<dim3(8, 8, 16), 256, 0, stream>>>(Ycur, Zcur, T, Yalt, Zalt);
    float* tp;
    tp = Ycur; Ycur = Yalt; Yalt = tp;
    tp = Zcur; Zcur = Zalt; Zalt = tp;
  }

  whiten_pad<<<dim3(36, 4, 4), 256, 0, stream>>>(Zcur, scal, fc, fs, ncP, nsP, nsT);
  q_kernel<<<(B_ * NP_ + 3) / 4, 256, 0, stream>>>(nsP, q);
  kninv_kernel<<<(B_ * N_ + 255) / 256, 256, 0, stream>>>(q, kni);

  if (dual) {
    m_kernel<<<dim3(20, 20, 2), 256, 0, stream>>>(
        nsT, ncP, Mb, (size_t)C_ * NPS_, (size_t)MS_ * MS_);
    score_kernel<<<dim3(N_ / 256, NCH_, 2), 256, 0, stream>>>(
        Mb, kni, pval, pidx, 0, (size_t)MS_ * MS_);
  } else {
    for (int b = 0; b < B_; b++) {
      m_kernel<<<dim3(20, 20, 1), 256, 0, stream>>>(
          nsT + (size_t)b * C_ * NPS_, ncP + (size_t)b * C_ * NPS_, Mb, 0, 0);
      score_kernel<<<dim3(N_ / 256, NCH_, 1), 256, 0, stream>>>(
          Mb, kni, pval, pidx, b, 0);
    }
  }
  argmax_final<<<(B_ * N_ + 255) / 256, 256, 0, stream>>>(pval, pidx, idxb);
  reassemble_kernel<<<B_ * N_, 256, 0, stream>>>(nsP, idxb, recon);
  rmean_part<<<dim3(16, B_), 256, 0, stream>>>(recon, pmr);
  rmean_fin<<<B_, 256, 0, stream>>>(pmr, mr);
  color_blend<<<dim3(36, 4, B_), 256, 0, stream>>>(
      Ycur, scal, recon, mr, msty, content, ssp, out);
}

// Round 12
// 357.083 us; speedup vs baseline: 1.0970x; 1.0970x over previous
//
#include <hip/hip_runtime.h>

// Problem constants (setup_inputs: B=2, C=256, H=W=48, p=3)
constexpr int B_  = 2;
constexpr int C_  = 256;
constexpr int H_  = 48;
constexpr int W_  = 48;
constexpr int N_  = H_ * W_;          // 2304
constexpr int PH_ = H_ + 2;           // 50
constexpr int PW_ = W_ + 2;           // 50
constexpr int NP_ = PH_ * PW_;        // 2500
constexpr int NPS_ = 2560;            // k-major row stride
constexpr int MS_  = 2560;            // M row stride (padded)
constexpr int CC_ = C_ * C_;          // 65536
constexpr int NCH_ = 36;              // n-chunks for score partial argmax
constexpr int NC_  = N_ / NCH_;       // 64
constexpr int NSIT_ = 5;              // Newton-Schulz iterations (e5 ~ 5e-10)
constexpr int KCH_ = 9;               // cov K-chunks (2304 = 9*256)

// ---------------- reduction helpers ----------------
__device__ inline float waveRed(float v) {
  #pragma unroll
  for (int o = 32; o > 0; o >>= 1) v += __shfl_down(v, o);
  return v;
}

// 16-FMA inner step on staged 64-wide tiles
#define GEMM64_COMPUTE(sAT, sB, acc, ty, tx)                        \
  _Pragma("unroll")                                                 \
  for (int kk = 0; kk < 16; kk++) {                                 \
    float4 a = *(const float4*)&sAT[kk][(ty) * 4];                  \
    float4 b = *(const float4*)&sB[kk][(tx) * 4];                   \
    acc[0][0] += a.x * b.x; acc[0][1] += a.x * b.y;                 \
    acc[0][2] += a.x * b.z; acc[0][3] += a.x * b.w;                 \
    acc[1][0] += a.y * b.x; acc[1][1] += a.y * b.y;                 \
    acc[1][2] += a.y * b.z; acc[1][3] += a.y * b.w;                 \
    acc[2][0] += a.z * b.x; acc[2][1] += a.z * b.y;                 \
    acc[2][2] += a.z * b.z; acc[2][3] += a.z * b.w;                 \
    acc[3][0] += a.w * b.x; acc[3][1] += a.w * b.y;                 \
    acc[3][2] += a.w * b.z; acc[3][3] += a.w * b.w;                 \
  }

// ---------------- kernels ----------------

// Per-(b,c) mean over N (float4), write centered rows. which=0: content->fc, 1: style->fs
__global__ __launch_bounds__(256) void center_kernel(
    const float* __restrict__ content, const float* __restrict__ style,
    float* __restrict__ fc, float* __restrict__ fs, float* __restrict__ mean_s) {
  int t = blockIdx.x;
  int which = t / (B_ * C_);
  int bc = t % (B_ * C_);
  const float* src = which ? style : content;
  float* dst = which ? fs : fc;
  const float4* row4 = (const float4*)(src + (size_t)bc * N_);
  float4* dst4 = (float4*)(dst + (size_t)bc * N_);
  float acc = 0.f;
  for (int i = threadIdx.x; i < N_ / 4; i += 256) {
    float4 v = row4[i];
    acc += v.x + v.y + v.z + v.w;
  }
  __shared__ float sm[4];
  float r = waveRed(acc);
  if ((threadIdx.x & 63) == 0) sm[threadIdx.x >> 6] = r;
  __syncthreads();
  float mean = (sm[0] + sm[1] + sm[2] + sm[3]) * (1.0f / N_);
  for (int i = threadIdx.x; i < N_ / 4; i += 256) {
    float4 v = row4[i];
    v.x -= mean; v.y -= mean; v.z -= mean; v.w -= mean;
    dst4[i] = v;
  }
  if (which == 1 && threadIdx.x == 0) mean_s[bc] = mean;
}

// K-split covariance partials: z = ci*4+m. 64x64 tile, both operands transposed-staged.
__global__ __launch_bounds__(256) void cov_kernel(
    const float* __restrict__ fc, const float* __restrict__ fs, float* __restrict__ pcov) {
  int z = blockIdx.z;
  int m = z & 3, ci = z >> 2;
  const float* f = (m < 2) ? (fc + (size_t)m * C_ * N_) : (fs + (size_t)(m - 2) * C_ * N_);
  int i0 = blockIdx.y * 64, j0 = blockIdx.x * 64;
  int t = threadIdx.x;
  int tx = t & 15, ty = t >> 4;
  int sr = t >> 2, skq = t & 3;
  __shared__ float sAT[16][68], sB[16][68];
  float acc[4][4] = {};
  int k0e = ci * 256 + 256;
  for (int k0 = ci * 256; k0 < k0e; k0 += 16) {
    float4 av = *(const float4*)&f[(size_t)(i0 + sr) * N_ + k0 + skq * 4];
    float4 bv = *(const float4*)&f[(size_t)(j0 + sr) * N_ + k0 + skq * 4];
    __syncthreads();
    sAT[skq * 4 + 0][sr] = av.x; sAT[skq * 4 + 1][sr] = av.y;
    sAT[skq * 4 + 2][sr] = av.z; sAT[skq * 4 + 3][sr] = av.w;
    sB[skq * 4 + 0][sr] = bv.x;  sB[skq * 4 + 1][sr] = bv.y;
    sB[skq * 4 + 2][sr] = bv.z;  sB[skq * 4 + 3][sr] = bv.w;
    __syncthreads();
    GEMM64_COMPUTE(sAT, sB, acc, ty, tx)
  }
  float* out = pcov + ((size_t)ci * 4 + m) * CC_;
  for (int u = 0; u < 4; u++)
    for (int v = 0; v < 4; v++)
      out[(size_t)(i0 + ty * 4 + u) * C_ + (j0 + tx * 4 + v)] = acc[u][v];
}

// A4[m] = (sum_ci pcov[ci][m]) / (N-1)
__global__ __launch_bounds__(256) void covreduce(
    const float* __restrict__ pcov, float* __restrict__ A4) {
  int t = blockIdx.x * 256 + threadIdx.x;
  float acc = 0.f;
  #pragma unroll
  for (int ci = 0; ci < KCH_; ci++) acc += pcov[(size_t)ci * 4 * CC_ + t];
  A4[t] = acc * (1.0f / (float)(N_ - 1));
}

// 2-partial init: Yp[p0]=A/s, Yp[p1]=0; Zp[p0]=I, Zp[p1]=0. grid (16,4)
__global__ __launch_bounds__(256) void ns_init(
    const float* __restrict__ A4, float* __restrict__ Yp, float* __restrict__ Zp,
    float* __restrict__ scal) {
  int m = blockIdx.y, s = blockIdx.x;
  const float* A = A4 + (size_t)m * CC_;
  float d = A[(size_t)threadIdx.x * 257];
  __shared__ float sm[4];
  float r = waveRed(d);
  if ((threadIdx.x & 63) == 0) sm[threadIdx.x >> 6] = r;
  __syncthreads();
  float trace = sm[0] + sm[1] + sm[2] + sm[3];
  float sc = 1.1f * trace / (float)C_;
  if (s == 0 && threadIdx.x == 0) scal[m] = sc;
  float inv = 1.0f / sc;
  int i0 = s * (CC_ / 16);
  for (int i = i0 + threadIdx.x; i < i0 + CC_ / 16; i += 256) {
    Yp[(size_t)m * CC_ + i] = A[i] * inv;
    Zp[(size_t)m * CC_ + i] = ((i >> 8) == (i & 255)) ? 1.0f : 0.0f;
    Yp[(size_t)(4 + m) * CC_ + i] = 0.f;
    Zp[(size_t)(4 + m) * CC_ + i] = 0.f;
  }
}

// T_kh = (kh==0?3I:0) - (Zp0+Zp1)(Yp0+Yp1) over K in [kh*128,(kh+1)*128).
// 32x32 tiles, BK=32. grid (8,8,8): z = kh*4+m
__global__ __launch_bounds__(256) void ns_stepA(
    const float* __restrict__ Zp, const float* __restrict__ Yp, float* __restrict__ Tp) {
  int z = blockIdx.z;
  int m = z & 3, kh = z >> 2;
  const float* A0 = Zp + (size_t)m * CC_;
  const float* A1 = Zp + (size_t)(4 + m) * CC_;
  const float* B0 = Yp + (size_t)m * CC_;
  const float* B1 = Yp + (size_t)(4 + m) * CC_;
  float* out = Tp + (size_t)(kh * 4 + m) * CC_;
  int i0 = blockIdx.y * 32, j0 = blockIdx.x * 32;
  int t = threadIdx.x;
  int tx = t & 15, ty = t >> 4;
  int sr = t >> 3, sc4 = t & 7;
  __shared__ float sAT[32][36], sB[32][36];
  float acc[2][2] = {};
  int k0e = kh * 128 + 128;
  for (int k0 = kh * 128; k0 < k0e; k0 += 32) {
    size_t ia = (size_t)(i0 + sr) * 256 + k0 + sc4 * 4;
    size_t ib = (size_t)(k0 + sr) * 256 + j0 + sc4 * 4;
    float4 a0 = *(const float4*)&A0[ia];
    float4 a1 = *(const float4*)&A1[ia];
    float4 b0 = *(const float4*)&B0[ib];
    float4 b1 = *(const float4*)&B1[ib];
    float4 av = {a0.x + a1.x, a0.y + a1.y, a0.z + a1.z, a0.w + a1.w};
    float4 bv = {b0.x + b1.x, b0.y + b1.y, b0.z + b1.z, b0.w + b1.w};
    __syncthreads();
    sAT[sc4 * 4 + 0][sr] = av.x; sAT[sc4 * 4 + 1][sr] = av.y;
    sAT[sc4 * 4 + 2][sr] = av.z; sAT[sc4 * 4 + 3][sr] = av.w;
    *(float4*)&sB[sr][sc4 * 4] = bv;
    __syncthreads();
    #pragma unroll
    for (int kk = 0; kk < 32; kk++) {
      float2 a = *(const float2*)&sAT[kk][ty * 2];
      float2 b = *(const float2*)&sB[kk][tx * 2];
      acc[0][0] += a.x * b.x; acc[0][1] += a.x * b.y;
      acc[1][0] += a.y * b.x; acc[1][1] += a.y * b.y;
    }
    __syncthreads();
  }
  for (int u = 0; u < 2; u++)
    for (int v = 0; v < 2; v++) {
      int i = i0 + ty * 2 + u, j = j0 + tx * 2 + v;
      float d = (kh == 0 && i == j) ? 3.0f : 0.0f;
      out[(size_t)i * 256 + j] = d - acc[u][v];
    }
}

// grid (8,8,16): m=z&3, kh=(z>>2)&1, doY=z<8. Yn_kh=0.5*Y*T | Zn_kh=0.5*T*Z (K-restricted)
__global__ __launch_bounds__(256) void ns_stepB(
    const float* __restrict__ Yp, const float* __restrict__ Zp, const float* __restrict__ Tp,
    float* __restrict__ Ynp, float* __restrict__ Znp) {
  int z = blockIdx.z;
  int m = z & 3, kh = (z >> 2) & 1;
  bool doY = (z < 8);
  const float* A0 = (doY ? Yp : Tp) + (size_t)m * CC_;
  const float* A1 = (doY ? Yp : Tp) + (size_t)(4 + m) * CC_;
  const float* B0 = (doY ? Tp : Zp) + (size_t)m * CC_;
  const float* B1 = (doY ? Tp : Zp) + (size_t)(4 + m) * CC_;
  float* out = (doY ? Ynp : Znp) + (size_t)(kh * 4 + m) * CC_;
  int i0 = blockIdx.y * 32, j0 = blockIdx.x * 32;
  int t = threadIdx.x;
  int tx = t & 15, ty = t >> 4;
  int sr = t >> 3, sc4 = t & 7;
  __shared__ float sAT[32][36], sB[32][36];
  float acc[2][2] = {};
  int k0e = kh * 128 + 128;
  for (int k0 = kh * 128; k0 < k0e; k0 += 32) {
    size_t ia = (size_t)(i0 + sr) * 256 + k0 + sc4 * 4;
    size_t ib = (size_t)(k0 + sr) * 256 + j0 + sc4 * 4;
    float4 a0 = *(const float4*)&A0[ia];
    float4 a1 = *(const float4*)&A1[ia];
    float4 b0 = *(const float4*)&B0[ib];
    float4 b1 = *(const float4*)&B1[ib];
    float4 av = {a0.x + a1.x, a0.y + a1.y, a0.z + a1.z, a0.w + a1.w};
    float4 bv = {b0.x + b1.x, b0.y + b1.y, b0.z + b1.z, b0.w + b1.w};
    __syncthreads();
    sAT[sc4 * 4 + 0][sr] = av.x; sAT[sc4 * 4 + 1][sr] = av.y;
    sAT[sc4 * 4 + 2][sr] = av.z; sAT[sc4 * 4 + 3][sr] = av.w;
    *(float4*)&sB[sr][sc4 * 4] = bv;
    __syncthreads();
    #pragma unroll
    for (int kk = 0; kk < 32; kk++) {
      float2 a = *(const float2*)&sAT[kk][ty * 2];
      float2 b = *(const float2*)&sB[kk][tx * 2];
      acc[0][0] += a.x * b.x; acc[0][1] += a.x * b.y;
      acc[1][0] += a.y * b.x; acc[1][1] += a.y * b.y;
    }
    __syncthreads();
  }
  for (int u = 0; u < 2; u++)
    for (int v = 0; v < 2; v++) {
      int i = i0 + ty * 2 + u, j = j0 + tx * 2 + v;
      out[(size_t)i * 256 + j] = 0.5f * acc[u][v];
    }
}

// (Zp0+Zp1)/sqrt(s) * f -> padded buffers. m<2: content -> ncP [b][c][NPS] (k-major);
// m>=2: style -> nsP [b][NP][c] AND nsT [b][c][NPS] (k-major).  grid (36,4,4)
__global__ __launch_bounds__(256) void whiten_pad(
    const float* __restrict__ Zf, const float* __restrict__ scal,
    const float* __restrict__ fc, const float* __restrict__ fs,
    float* __restrict__ ncP, float* __restrict__ nsP, float* __restrict__ nsT) {
  int m = blockIdx.z;
  const float* f = (m < 2) ? (fc + (size_t)m * C_ * N_) : (fs + (size_t)(m - 2) * C_ * N_);
  int c0 = blockIdx.y * 64, x0 = blockIdx.x * 64;
  int t = threadIdx.x;
  int tx = t & 15, ty = t >> 4;
  int sr = t >> 2, skq = t & 3;
  int bkk = t & 15, bc4 = t >> 4;
  __shared__ float sAT[16][68], sB[16][68];
  float acc[4][4] = {};
  for (int k0 = 0; k0 < 256; k0 += 16) {
    size_t ia = (size_t)(c0 + sr) * 256 + k0 + skq * 4;
    float4 a0 = *(const float4*)&Zf[(size_t)m * CC_ + ia];
    float4 a1 = *(const float4*)&Zf[(size_t)(4 + m) * CC_ + ia];
    float4 av = {a0.x + a1.x, a0.y + a1.y, a0.z + a1.z, a0.w + a1.w};
    float4 bv = *(const float4*)&f[(size_t)(k0 + bkk) * N_ + x0 + bc4 * 4];
    __syncthreads();
    sAT[skq * 4 + 0][sr] = av.x; sAT[skq * 4 + 1][sr] = av.y;
    sAT[skq * 4 + 2][sr] = av.z; sAT[skq * 4 + 3][sr] = av.w;
    *(float4*)&sB[bkk][bc4 * 4] = bv;
    __syncthreads();
    GEMM64_COMPUTE(sAT, sB, acc, ty, tx)
  }
  float rs = rsqrtf(scal[m]);
  int b = (m < 2) ? m : (m - 2);
  for (int u = 0; u < 4; u++)
    for (int v = 0; v < 4; v++) {
      int c = c0 + ty * 4 + u, x = x0 + tx * 4 + v;
      int h = x / W_, w = x % W_;
      int pp = (h + 1) * PW_ + (w + 1);
      float val = acc[u][v] * rs;
      if (m < 2) {
        ncP[((size_t)b * C_ + c) * NPS_ + pp] = val;
      } else {
        nsP[((size_t)b * NP_ + pp) * C_ + c] = val;
        nsT[((size_t)b * C_ + c) * NPS_ + pp] = val;
      }
    }
}

// q[b][p] = sum_c nsP[b][p][c]^2
__global__ __launch_bounds__(256) void q_kernel(const float* __restrict__ nsP, float* __restrict__ q) {
  int wid = (blockIdx.x * 256 + threadIdx.x) >> 6;
  int lane = threadIdx.x & 63;
  if (wid >= B_ * NP_) return;
  const float* v = nsP + (size_t)wid * C_;
  float acc = 0.f;
  #pragma unroll
  for (int c = lane; c < C_; c += 64) { float t = v[c]; acc += t * t; }
  acc = waveRed(acc);
  if (lane == 0) q[wid] = acc;
}

// kninv[b][n] = rsqrt( sum over 3x3 of q )
__global__ __launch_bounds__(256) void kninv_kernel(const float* __restrict__ q, float* __restrict__ kninv) {
  int t = blockIdx.x * 256 + threadIdx.x;
  if (t >= B_ * N_) return;
  int b = t / N_, n = t % N_;
  int hn = n / W_, wn = n % W_;
  const float* qb = q + (size_t)b * NP_ + hn * PW_ + wn;
  float s = 0.f;
  #pragma unroll
  for (int i = 0; i < 3; i++)
    #pragma unroll
    for (int j = 0; j < 3; j++) s += qb[i * PW_ + j];
  kninv[t] = rsqrtf(s);
}

// M[i][j] = sum_k At[k][i]*Bt[k][j]; both k-major (stride NPS_), M padded stride MS_.
// Tile 64(i) x 128(j); acc[4][8]; BK=32 single-buffer (R8 proven, 44 VGPR no spill).
// blockIdx.z = batch.
__global__ __launch_bounds__(256) void m_kernel(
    const float* __restrict__ At, const float* __restrict__ Bt, float* __restrict__ M,
    size_t batchA, size_t batchM) {
  size_t bz = blockIdx.z;
  At += bz * batchA; Bt += bz * batchA; M += bz * batchM;
  int i0 = blockIdx.y * 64, j0 = blockIdx.x * 128;
  int t = threadIdx.x;
  int tx = t & 15, ty = t >> 4;
  int ak = t >> 4, ac = t & 15;
  int bk = t >> 5, bc = t & 31;
  __shared__ float sA[32][68], sB[32][132];
  float acc[4][8] = {};
  for (int k0 = 0; k0 < 256; k0 += 32) {
    float4 a0 = *(const float4*)&At[(size_t)(k0 + ak) * NPS_ + i0 + ac * 4];
    float4 a1 = *(const float4*)&At[(size_t)(k0 + ak + 16) * NPS_ + i0 + ac * 4];
    float4 b0 = *(const float4*)&Bt[(size_t)(k0 + bk) * NPS_ + j0 + bc * 4];
    float4 b1 = *(const float4*)&Bt[(size_t)(k0 + bk + 8) * NPS_ + j0 + bc * 4];
    float4 b2 = *(const float4*)&Bt[(size_t)(k0 + bk + 16) * NPS_ + j0 + bc * 4];
    float4 b3 = *(const float4*)&Bt[(size_t)(k0 + bk + 24) * NPS_ + j0 + bc * 4];
    __syncthreads();
    *(float4*)&sA[ak][ac * 4] = a0;
    *(float4*)&sA[ak + 16][ac * 4] = a1;
    *(float4*)&sB[bk][bc * 4] = b0;
    *(float4*)&sB[bk + 8][bc * 4] = b1;
    *(float4*)&sB[bk + 16][bc * 4] = b2;
    *(float4*)&sB[bk + 24][bc * 4] = b3;
    __syncthreads();
    #pragma unroll
    for (int kk = 0; kk < 32; kk++) {
      float4 a  = *(const float4*)&sA[kk][ty * 4];
      float4 p  = *(const float4*)&sB[kk][tx * 4];
      float4 qv = *(const float4*)&sB[kk][64 + tx * 4];
      acc[0][0] += a.x * p.x; acc[0][1] += a.x * p.y; acc[0][2] += a.x * p.z; acc[0][3] += a.x * p.w;
      acc[1][0] += a.y * p.x; acc[1][1] += a.y * p.y; acc[1][2] += a.y * p.z; acc[1][3] += a.y * p.w;
      acc[2][0] += a.z * p.x; acc[2][1] += a.z * p.y; acc[2][2] += a.z * p.z; acc[2][3] += a.z * p.w;
      acc[3][0] += a.w * p.x; acc[3][1] += a.w * p.y; acc[3][2] += a.w * p.z; acc[3][3] += a.w * p.w;
      acc[0][4] += a.x * qv.x; acc[0][5] += a.x * qv.y; acc[0][6] += a.x * qv.z; acc[0][7] += a.x * qv.w;
      acc[1][4] += a.y * qv.x; acc[1][5] += a.y * qv.y; acc[1][6] += a.y * qv.z; acc[1][7] += a.y * qv.w;
      acc[2][4] += a.z * qv.x; acc[2][5] += a.z * qv.y; acc[2][6] += a.z * qv.z; acc[2][7] += a.z * qv.w;
      acc[3][4] += a.w * qv.x; acc[3][5] += a.w * qv.y; acc[3][6] += a.w * qv.z; acc[3][7] += a.w * qv.w;
    }
    __syncthreads();
  }
  #pragma unroll
  for (int u = 0; u < 4; u++) {
    size_t row = (size_t)(i0 + ty * 4 + u) * MS_;
    float4 s0 = {acc[u][0], acc[u][1], acc[u][2], acc[u][3]};
    float4 s1 = {acc[u][4], acc[u][5], acc[u][6], acc[u][7]};
    *(float4*)&M[row + j0 + tx * 4] = s0;
    *(float4*)&M[row + j0 + 64 + tx * 4] = s1;
  }
}

// Partial argmax over an n-chunk for each content position m. (M stride MS_)
// batch = b0 + blockIdx.z; M offset by blockIdx.z * batchM.
__global__ __launch_bounds__(256) void score_kernel(
    const float* __restrict__ M, const float* __restrict__ kninv,
    float* __restrict__ pval, int* __restrict__ pidx, int b0, size_t batchM) {
  int b = b0 + blockIdx.z;
  M += (size_t)blockIdx.z * batchM;
  int m = blockIdx.x * 256 + threadIdx.x;
  int h = m / W_, w = m % W_;
  int cm = h * PW_ + w;
  int n0 = blockIdx.y * NC_;
  const float* kni = kninv + (size_t)b * N_;
  float best = -3.4e38f;
  int bidx = n0;
  for (int n = n0; n < n0 + NC_; n++) {
    int hn = n / W_, wn = n % W_;
    int rn = hn * PW_ + wn;
    const float* base = M + (size_t)rn * MS_ + cm;
    float s = 0.f;
    #pragma unroll
    for (int i = 0; i < 3; i++)
      #pragma unroll
      for (int j = 0; j < 3; j++) s += base[(size_t)(i * PW_ + j) * (MS_ + 1)];
    s *= kni[n];
    if (s > best) { best = s; bidx = n; }
  }
  pval[((size_t)b * NCH_ + blockIdx.y) * N_ + m] = best;
  pidx[((size_t)b * NCH_ + blockIdx.y) * N_ + m] = bidx;
}

// Final argmax across chunks (ascending => first-max wins, matches jnp.argmax)
__global__ __launch_bounds__(256) void argmax_final(
    const float* __restrict__ pval, const int* __restrict__ pidx, int* __restrict__ idxb) {
  int t = blockIdx.x * 256 + threadIdx.x;
  if (t >= B_ * N_) return;
  int b = t / N_, m = t % N_;
  float best = -3.4e38f; int bidx = 0;
  for (int ch = 0; ch < NCH_; ch++) {
    float v = pval[((size_t)b * NCH_ + ch) * N_ + m];
    int i = pidx[((size_t)b * NCH_ + ch) * N_ + m];
    if (v > best) { best = v; bidx = i; }
  }
  idxb[t] = bidx;
}

// Overlap-add reassembly: recon[b][m][c] (position-major).
// One WAVE per position; lanes cover channels as float4. grid = B*N/4 blocks.
__global__ __launch_bounds__(256) void reassemble_kernel(
    const float* __restrict__ nsP, const int* __restrict__ idxb, float* __restrict__ recon) {
  int t = threadIdx.x;
  int sub = t >> 6, lane = t & 63;
  int p = blockIdx.x * 4 + sub;          // global (b,m) index
  int b = p / N_, m = p % N_;
  int h = m / W_, w = m % W_;
  float4 acc = {0.f, 0.f, 0.f, 0.f};
  int cnt = 0;
  for (int di = 0; di < 3; di++) {
    int hs = h + 1 - di; if (hs < 0 || hs >= H_) continue;
    for (int dj = 0; dj < 3; dj++) {
      int ws = w + 1 - dj; if (ws < 0 || ws >= W_) continue;
      int n = idxb[(size_t)b * N_ + hs * W_ + ws];
      int hn = n / W_, wn = n % W_;
      int pp = (hn + di) * PW_ + (wn + dj);
      float4 v = *(const float4*)&nsP[((size_t)b * NP_ + pp) * C_ + lane * 4];
      acc.x += v.x; acc.y += v.y; acc.z += v.z; acc.w += v.w;
      cnt++;
    }
  }
  float inv = 1.0f / (float)cnt;
  acc.x *= inv; acc.y *= inv; acc.z *= inv; acc.w *= inv;
  *(float4*)&recon[((size_t)b * N_ + m) * C_ + lane * 4] = acc;
}

// Partial column sums of recon over x-chunks
__global__ __launch_bounds__(256) void rmean_part(const float* __restrict__ recon, float* __restrict__ pmr) {
  int b = blockIdx.y, ch = blockIdx.x, c = threadIdx.x;
  float acc = 0.f;
  int x0 = ch * (N_ / 16);
  for (int x = x0; x < x0 + (N_ / 16); x++) acc += recon[((size_t)b * N_ + x) * C_ + c];
  pmr[((size_t)b * 16 + ch) * C_ + c] = acc;
}

__global__ __launch_bounds__(256) void rmean_fin(const float* __restrict__ pmr, float* __restrict__ mr) {
  int b = blockIdx.x, c = threadIdx.x;
  float acc = 0.f;
  for (int ch = 0; ch < 16; ch++) acc += pmr[((size_t)b * 16 + ch) * C_ + c];
  mr[(size_t)b * C_ + c] = acc * (1.0f / N_);
}

// stylized = sqrt(cov_s)*(recon-mr) + mean_s ; out = (1-ss)*content + ss*stylized
// grid (36,4,2). A = (Yp0+Yp1) (style matrix m=2+b)
__global__ __launch_bounds__(256) void color_blend(
    const float* __restrict__ Yf, const float* __restrict__ scal,
    const float* __restrict__ recon, const float* __restrict__ mr,
    const float* __restrict__ msty, const float* __restrict__ content,
    const float* __restrict__ ssp, float* __restrict__ out) {
  int b = blockIdx.z;
  int m = 2 + b;
  int c0 = blockIdx.y * 64, x0 = blockIdx.x * 64;
  int t = threadIdx.x;
  int tx = t & 15, ty = t >> 4;
  int sr = t >> 2, skq = t & 3;
  __shared__ float sAT[16][68], sB[16][68];
  float acc[4][4] = {};
  for (int k0 = 0; k0 < 256; k0 += 16) {
    size_t ia = (size_t)(c0 + sr) * 256 + k0 + skq * 4;
    float4 a0 = *(const float4*)&Yf[(size_t)m * CC_ + ia];
    float4 a1 = *(const float4*)&Yf[(size_t)(4 + m) * CC_ + ia];
    float4 av = {a0.x + a1.x, a0.y + a1.y, a0.z + a1.z, a0.w + a1.w};
    float4 bm4 = *(const float4*)&mr[(size_t)b * C_ + k0 + skq * 4];
    float4 bv = *(const float4*)&recon[((size_t)b * N_ + x0 + sr) * C_ + k0 + skq * 4];
    bv.x -= bm4.x; bv.y -= bm4.y; bv.z -= bm4.z; bv.w -= bm4.w;
    __syncthreads();
    sAT[skq * 4 + 0][sr] = av.x; sAT[skq * 4 + 1][sr] = av.y;
    sAT[skq * 4 + 2][sr] = av.z; sAT[skq * 4 + 3][sr] = av.w;
    sB[skq * 4 + 0][sr] = bv.x;  sB[skq * 4 + 1][sr] = bv.y;
    sB[skq * 4 + 2][sr] = bv.z;  sB[skq * 4 + 3][sr] = bv.w;
    __syncthreads();
    GEMM64_COMPUTE(sAT, sB, acc, ty, tx)
  }
  float sq = sqrtf(scal[m]);
  float ss = ssp[0];
  for (int u = 0; u < 4; u++)
    for (int v = 0; v < 4; v++) {
      int c = c0 + ty * 4 + u, x = x0 + tx * 4 + v;
      float sty = acc[u][v] * sq + msty[(size_t)b * C_ + c];
      size_t o = ((size_t)b * C_ + c) * N_ + x;
      out[o] = (1.0f - ss) * content[o] + ss * sty;
    }
}

// ---------------- host launch ----------------
extern "C" void kernel_launch(void* const* d_in, const int* in_sizes, int n_in,
                              void* d_out, int out_size, void* d_ws, size_t ws_size,
                              hipStream_t stream) {
  (void)in_sizes; (void)n_in; (void)out_size;
  const float* content = (const float*)d_in[0];
  const float* style   = (const float*)d_in[1];
  const float* ssp     = (const float*)d_in[2];
  float* out = (float*)d_out;
  float* W = (float*)d_ws;

  // workspace layout (floats)
  size_t off = 0;
  float* fc   = W + off; off += (size_t)B_ * C_ * N_;
  float* fs   = W + off; off += (size_t)B_ * C_ * N_;   // recon aliases fs later
  float* nsP  = W + off; off += (size_t)B_ * NP_ * C_;
  float* nsT  = W + off; off += (size_t)B_ * C_ * NPS_;
  float* ncP  = W + off; off += (size_t)B_ * C_ * NPS_;
  float* A4   = W + off; off += (size_t)4 * CC_;
  float* Ya   = W + off; off += (size_t)8 * CC_;   // 2-partial sets
  float* Yb   = W + off; off += (size_t)8 * CC_;
  float* Za   = W + off; off += (size_t)8 * CC_;
  float* Zb   = W + off; off += (size_t)8 * CC_;
  float* scal = W + off; off += 4;
  float* msty = W + off; off += (size_t)B_ * C_;
  float* mr   = W + off; off += (size_t)B_ * C_;
  float* pmr  = W + off; off += (size_t)B_ * 16 * C_;
  float* q    = W + off; off += (size_t)B_ * NP_;
  float* kni  = W + off; off += (size_t)B_ * N_;
  float* pval = W + off; off += (size_t)B_ * NCH_ * N_;
  float* Mb   = W + off;
  size_t off_Mb = off;

  size_t off1 = off_Mb + (size_t)MS_ * MS_;        // single-M layout
  size_t off2 = off_Mb + (size_t)2 * MS_ * MS_;    // dual-M layout
  size_t tail = (size_t)B_ * NCH_ * N_ + (size_t)B_ * N_;   // pidx + idxb
  bool dual = ws_size >= (off2 + tail) * sizeof(float);
  size_t offM = dual ? off2 : off1;
  int* pidx = (int*)(W + offM);
  int* idxb = (int*)(W + offM + (size_t)B_ * NCH_ * N_);
  float* pcov = Mb;          // 9*4*CC = 2.36M floats (dead before m_kernel)
  float* T    = Mb;          // 8*CC floats; used only during NS
  float* recon = fs;         // fs dead after whiten_pad

  hipMemsetAsync(nsP, 0, (size_t)B_ * NP_ * C_ * sizeof(float), stream);
  hipMemsetAsync(nsT, 0, (size_t)B_ * C_ * NPS_ * sizeof(float), stream);
  hipMemsetAsync(ncP, 0, (size_t)B_ * C_ * NPS_ * sizeof(float), stream);

  center_kernel<<<2 * B_ * C_, 256, 0, stream>>>(content, style, fc, fs, msty);
  cov_kernel<<<dim3(4, 4, 4 * KCH_), 256, 0, stream>>>(fc, fs, pcov);
  covreduce<<<4 * CC_ / 256, 256, 0, stream>>>(pcov, A4);
  ns_init<<<dim3(16, 4), 256, 0, stream>>>(A4, Ya, Za, scal);

  float *Ycur = Ya, *Zcur = Za, *Yalt = Yb, *Zalt = Zb;
  for (int it = 0; it < NSIT_; it++) {
    ns_stepA<<<dim3(8, 8, 8), 256, 0, stream>>>(Zcur, Ycur, T);
    ns_stepB<<<dim3(8, 8, 16), 256, 0, stream>>>(Ycur, Zcur, T, Yalt, Zalt);
    float* tp;
    tp = Ycur; Ycur = Yalt; Yalt = tp;
    tp = Zcur; Zcur = Zalt; Zalt = tp;
  }

  whiten_pad<<<dim3(36, 4, 4), 256, 0, stream>>>(Zcur, scal, fc, fs, ncP, nsP, nsT);
  q_kernel<<<(B_ * NP_ + 3) / 4, 256, 0, stream>>>(nsP, q);
  kninv_kernel<<<(B_ * N_ + 255) / 256, 256, 0, stream>>>(q, kni);

  if (dual) {
    m_kernel<<<dim3(20, 40, 2), 256, 0, stream>>>(
        nsT, ncP, Mb, (size_t)C_ * NPS_, (size_t)MS_ * MS_);
    score_kernel<<<dim3(N_ / 256, NCH_, 2), 256, 0, stream>>>(
        Mb, kni, pval, pidx, 0, (size_t)MS_ * MS_);
  } else {
    for (int b = 0; b < B_; b++) {
      m_kernel<<<dim3(20, 40, 1), 256, 0, stream>>>(
          nsT + (size_t)b * C_ * NPS_, ncP + (size_t)b * C_ * NPS_, Mb, 0, 0);
      score_kernel<<<dim3(N_ / 256, NCH_, 1), 256, 0, stream>>>(
          Mb, kni, pval, pidx, b, 0);
    }
  }
  argmax_final<<<(B_ * N_ + 255) / 256, 256, 0, stream>>>(pval, pidx, idxb);
  reassemble_kernel<<<B_ * N_ / 4, 256, 0, stream>>>(nsP, idxb, recon);
  rmean_part<<<dim3(16, B_), 256, 0, stream>>>(recon, pmr);
  rmean_fin<<<B_, 256, 0, stream>>>(pmr, mr);
  color_blend<<<dim3(36, 4, B_), 256, 0, stream>>>(
      Ycur, scal, recon, mr, msty, content, ssp, out);
}

// Round 13
// 351.325 us; speedup vs baseline: 1.1150x; 1.0164x over previous
//
#include <hip/hip_runtime.h>

// Problem constants (setup_inputs: B=2, C=256, H=W=48, p=3)
constexpr int B_  = 2;
constexpr int C_  = 256;
constexpr int H_  = 48;
constexpr int W_  = 48;
constexpr int N_  = H_ * W_;          // 2304
constexpr int PH_ = H_ + 2;           // 50
constexpr int PW_ = W_ + 2;           // 50
constexpr int NP_ = PH_ * PW_;        // 2500
constexpr int NPS_ = 2560;            // k-major row stride
constexpr int MS_  = 2560;            // M row stride (padded)
constexpr int CC_ = C_ * C_;          // 65536
constexpr int NCH_ = 36;              // n-chunks for score partial argmax
constexpr int NC_  = N_ / NCH_;       // 64
constexpr int NSIT_ = 5;              // Newton-Schulz iterations (e5 ~ 5e-10)
constexpr int KCH_ = 9;               // cov K-chunks (2304 = 9*256)

// ---------------- reduction helpers ----------------
__device__ inline float waveRed(float v) {
  #pragma unroll
  for (int o = 32; o > 0; o >>= 1) v += __shfl_down(v, o);
  return v;
}

// 16-FMA inner step on staged 64-wide tiles
#define GEMM64_COMPUTE(sAT, sB, acc, ty, tx)                        \
  _Pragma("unroll")                                                 \
  for (int kk = 0; kk < 16; kk++) {                                 \
    float4 a = *(const float4*)&sAT[kk][(ty) * 4];                  \
    float4 b = *(const float4*)&sB[kk][(tx) * 4];                   \
    acc[0][0] += a.x * b.x; acc[0][1] += a.x * b.y;                 \
    acc[0][2] += a.x * b.z; acc[0][3] += a.x * b.w;                 \
    acc[1][0] += a.y * b.x; acc[1][1] += a.y * b.y;                 \
    acc[1][2] += a.y * b.z; acc[1][3] += a.y * b.w;                 \
    acc[2][0] += a.z * b.x; acc[2][1] += a.z * b.y;                 \
    acc[2][2] += a.z * b.z; acc[2][3] += a.z * b.w;                 \
    acc[3][0] += a.w * b.x; acc[3][1] += a.w * b.y;                 \
    acc[3][2] += a.w * b.z; acc[3][3] += a.w * b.w;                 \
  }

// ---------------- kernels ----------------

// Zero only the padding the GEMM/compute kernels never write:
// blocks [0,512): row (b*C+c) of nsT & ncP — 196 border pps + 60 stride-tail slots.
// blocks [512,904): nsP border positions, all 256 channels (contiguous).
__global__ __launch_bounds__(256) void border_zero(
    float* __restrict__ nsP, float* __restrict__ nsT, float* __restrict__ ncP) {
  int blk = blockIdx.x;
  if (blk < 512) {
    int row = blk;
    int s = threadIdx.x;
    int pp;
    if (s < 50)       pp = s;                          // h=0 row
    else if (s < 100) pp = 49 * 50 + (s - 50);         // h=49 row
    else if (s < 148) pp = (s - 100 + 1) * 50;         // w=0 col, h=1..48
    else if (s < 196) pp = (s - 148 + 1) * 50 + 49;    // w=49 col, h=1..48
    else              pp = 2500 + (s - 196);           // stride tail 2500..2559
    nsT[(size_t)row * NPS_ + pp] = 0.f;
    ncP[(size_t)row * NPS_ + pp] = 0.f;
  } else {
    int idx = blk - 512;                               // 0..391
    int b = idx / 196, k = idx % 196;
    int pp;
    if (k < 50)       pp = k;
    else if (k < 100) pp = 49 * 50 + (k - 50);
    else if (k < 148) pp = (k - 100 + 1) * 50;
    else              pp = (k - 148 + 1) * 50 + 49;
    nsP[((size_t)b * NP_ + pp) * C_ + threadIdx.x] = 0.f;
  }
}

// Per-(b,c) mean over N (float4), write centered rows. which=0: content->fc, 1: style->fs
__global__ __launch_bounds__(256) void center_kernel(
    const float* __restrict__ content, const float* __restrict__ style,
    float* __restrict__ fc, float* __restrict__ fs, float* __restrict__ mean_s) {
  int t = blockIdx.x;
  int which = t / (B_ * C_);
  int bc = t % (B_ * C_);
  const float* src = which ? style : content;
  float* dst = which ? fs : fc;
  const float4* row4 = (const float4*)(src + (size_t)bc * N_);
  float4* dst4 = (float4*)(dst + (size_t)bc * N_);
  float acc = 0.f;
  for (int i = threadIdx.x; i < N_ / 4; i += 256) {
    float4 v = row4[i];
    acc += v.x + v.y + v.z + v.w;
  }
  __shared__ float sm[4];
  float r = waveRed(acc);
  if ((threadIdx.x & 63) == 0) sm[threadIdx.x >> 6] = r;
  __syncthreads();
  float mean = (sm[0] + sm[1] + sm[2] + sm[3]) * (1.0f / N_);
  for (int i = threadIdx.x; i < N_ / 4; i += 256) {
    float4 v = row4[i];
    v.x -= mean; v.y -= mean; v.z -= mean; v.w -= mean;
    dst4[i] = v;
  }
  if (which == 1 && threadIdx.x == 0) mean_s[bc] = mean;
}

// K-split covariance partials: z = ci*4+m. 64x64 tile, both operands transposed-staged.
__global__ __launch_bounds__(256) void cov_kernel(
    const float* __restrict__ fc, const float* __restrict__ fs, float* __restrict__ pcov) {
  int z = blockIdx.z;
  int m = z & 3, ci = z >> 2;
  const float* f = (m < 2) ? (fc + (size_t)m * C_ * N_) : (fs + (size_t)(m - 2) * C_ * N_);
  int i0 = blockIdx.y * 64, j0 = blockIdx.x * 64;
  int t = threadIdx.x;
  int tx = t & 15, ty = t >> 4;
  int sr = t >> 2, skq = t & 3;
  __shared__ float sAT[16][68], sB[16][68];
  float acc[4][4] = {};
  int k0e = ci * 256 + 256;
  for (int k0 = ci * 256; k0 < k0e; k0 += 16) {
    float4 av = *(const float4*)&f[(size_t)(i0 + sr) * N_ + k0 + skq * 4];
    float4 bv = *(const float4*)&f[(size_t)(j0 + sr) * N_ + k0 + skq * 4];
    __syncthreads();
    sAT[skq * 4 + 0][sr] = av.x; sAT[skq * 4 + 1][sr] = av.y;
    sAT[skq * 4 + 2][sr] = av.z; sAT[skq * 4 + 3][sr] = av.w;
    sB[skq * 4 + 0][sr] = bv.x;  sB[skq * 4 + 1][sr] = bv.y;
    sB[skq * 4 + 2][sr] = bv.z;  sB[skq * 4 + 3][sr] = bv.w;
    __syncthreads();
    GEMM64_COMPUTE(sAT, sB, acc, ty, tx)
  }
  float* out = pcov + ((size_t)ci * 4 + m) * CC_;
  for (int u = 0; u < 4; u++)
    for (int v = 0; v < 4; v++)
      out[(size_t)(i0 + ty * 4 + u) * C_ + (j0 + tx * 4 + v)] = acc[u][v];
}

// Fused covreduce + 2-partial init. Reads pcov directly:
// trace from pcov diagonals; Yp[p0] = (sum_ci pcov)/( (N-1)*s ); Zp[p0]=I; p1 parts = 0.
// grid (16,4): bx=slice, by=m
__global__ __launch_bounds__(256) void ns_init(
    const float* __restrict__ pcov, float* __restrict__ Yp, float* __restrict__ Zp,
    float* __restrict__ scal) {
  int m = blockIdx.y, s = blockIdx.x;
  // trace: diag element threadIdx.x summed over chunks
  float d = 0.f;
  #pragma unroll
  for (int ci = 0; ci < KCH_; ci++)
    d += pcov[((size_t)ci * 4 + m) * CC_ + (size_t)threadIdx.x * 257];
  __shared__ float sm[4];
  float r = waveRed(d);
  if ((threadIdx.x & 63) == 0) sm[threadIdx.x >> 6] = r;
  __syncthreads();
  float trace = (sm[0] + sm[1] + sm[2] + sm[3]) * (1.0f / (float)(N_ - 1));
  float sc = 1.1f * trace / (float)C_;
  if (s == 0 && threadIdx.x == 0) scal[m] = sc;
  float inv = 1.0f / ((float)(N_ - 1) * sc);
  int i0 = s * (CC_ / 16);
  for (int i = i0 + threadIdx.x; i < i0 + CC_ / 16; i += 256) {
    float acc = 0.f;
    #pragma unroll
    for (int ci = 0; ci < KCH_; ci++) acc += pcov[((size_t)ci * 4 + m) * CC_ + i];
    Yp[(size_t)m * CC_ + i] = acc * inv;
    Zp[(size_t)m * CC_ + i] = ((i >> 8) == (i & 255)) ? 1.0f : 0.0f;
    Yp[(size_t)(4 + m) * CC_ + i] = 0.f;
    Zp[(size_t)(4 + m) * CC_ + i] = 0.f;
  }
}

// T_kh = (kh==0?3I:0) - (Zp0+Zp1)(Yp0+Yp1) over K in [kh*128,(kh+1)*128).
// 32x32 tiles, BK=32. grid (8,8,8): z = kh*4+m
__global__ __launch_bounds__(256) void ns_stepA(
    const float* __restrict__ Zp, const float* __restrict__ Yp, float* __restrict__ Tp) {
  int z = blockIdx.z;
  int m = z & 3, kh = z >> 2;
  const float* A0 = Zp + (size_t)m * CC_;
  const float* A1 = Zp + (size_t)(4 + m) * CC_;
  const float* B0 = Yp + (size_t)m * CC_;
  const float* B1 = Yp + (size_t)(4 + m) * CC_;
  float* out = Tp + (size_t)(kh * 4 + m) * CC_;
  int i0 = blockIdx.y * 32, j0 = blockIdx.x * 32;
  int t = threadIdx.x;
  int tx = t & 15, ty = t >> 4;
  int sr = t >> 3, sc4 = t & 7;
  __shared__ float sAT[32][36], sB[32][36];
  float acc[2][2] = {};
  int k0e = kh * 128 + 128;
  for (int k0 = kh * 128; k0 < k0e; k0 += 32) {
    size_t ia = (size_t)(i0 + sr) * 256 + k0 + sc4 * 4;
    size_t ib = (size_t)(k0 + sr) * 256 + j0 + sc4 * 4;
    float4 a0 = *(const float4*)&A0[ia];
    float4 a1 = *(const float4*)&A1[ia];
    float4 b0 = *(const float4*)&B0[ib];
    float4 b1 = *(const float4*)&B1[ib];
    float4 av = {a0.x + a1.x, a0.y + a1.y, a0.z + a1.z, a0.w + a1.w};
    float4 bv = {b0.x + b1.x, b0.y + b1.y, b0.z + b1.z, b0.w + b1.w};
    __syncthreads();
    sAT[sc4 * 4 + 0][sr] = av.x; sAT[sc4 * 4 + 1][sr] = av.y;
    sAT[sc4 * 4 + 2][sr] = av.z; sAT[sc4 * 4 + 3][sr] = av.w;
    *(float4*)&sB[sr][sc4 * 4] = bv;
    __syncthreads();
    #pragma unroll
    for (int kk = 0; kk < 32; kk++) {
      float2 a = *(const float2*)&sAT[kk][ty * 2];
      float2 b = *(const float2*)&sB[kk][tx * 2];
      acc[0][0] += a.x * b.x; acc[0][1] += a.x * b.y;
      acc[1][0] += a.y * b.x; acc[1][1] += a.y * b.y;
    }
    __syncthreads();
  }
  for (int u = 0; u < 2; u++)
    for (int v = 0; v < 2; v++) {
      int i = i0 + ty * 2 + u, j = j0 + tx * 2 + v;
      float d = (kh == 0 && i == j) ? 3.0f : 0.0f;
      out[(size_t)i * 256 + j] = d - acc[u][v];
    }
}

// grid (8,8,16): m=z&3, kh=(z>>2)&1, doY=z<8. Yn_kh=0.5*Y*T | Zn_kh=0.5*T*Z (K-restricted)
__global__ __launch_bounds__(256) void ns_stepB(
    const float* __restrict__ Yp, const float* __restrict__ Zp, const float* __restrict__ Tp,
    float* __restrict__ Ynp, float* __restrict__ Znp) {
  int z = blockIdx.z;
  int m = z & 3, kh = (z >> 2) & 1;
  bool doY = (z < 8);
  const float* A0 = (doY ? Yp : Tp) + (size_t)m * CC_;
  const float* A1 = (doY ? Yp : Tp) + (size_t)(4 + m) * CC_;
  const float* B0 = (doY ? Tp : Zp) + (size_t)m * CC_;
  const float* B1 = (doY ? Tp : Zp) + (size_t)(4 + m) * CC_;
  float* out = (doY ? Ynp : Znp) + (size_t)(kh * 4 + m) * CC_;
  int i0 = blockIdx.y * 32, j0 = blockIdx.x * 32;
  int t = threadIdx.x;
  int tx = t & 15, ty = t >> 4;
  int sr = t >> 3, sc4 = t & 7;
  __shared__ float sAT[32][36], sB[32][36];
  float acc[2][2] = {};
  int k0e = kh * 128 + 128;
  for (int k0 = kh * 128; k0 < k0e; k0 += 32) {
    size_t ia = (size_t)(i0 + sr) * 256 + k0 + sc4 * 4;
    size_t ib = (size_t)(k0 + sr) * 256 + j0 + sc4 * 4;
    float4 a0 = *(const float4*)&A0[ia];
    float4 a1 = *(const float4*)&A1[ia];
    float4 b0 = *(const float4*)&B0[ib];
    float4 b1 = *(const float4*)&B1[ib];
    float4 av = {a0.x + a1.x, a0.y + a1.y, a0.z + a1.z, a0.w + a1.w};
    float4 bv = {b0.x + b1.x, b0.y + b1.y, b0.z + b1.z, b0.w + b1.w};
    __syncthreads();
    sAT[sc4 * 4 + 0][sr] = av.x; sAT[sc4 * 4 + 1][sr] = av.y;
    sAT[sc4 * 4 + 2][sr] = av.z; sAT[sc4 * 4 + 3][sr] = av.w;
    *(float4*)&sB[sr][sc4 * 4] = bv;
    __syncthreads();
    #pragma unroll
    for (int kk = 0; kk < 32; kk++) {
      float2 a = *(const float2*)&sAT[kk][ty * 2];
      float2 b = *(const float2*)&sB[kk][tx * 2];
      acc[0][0] += a.x * b.x; acc[0][1] += a.x * b.y;
      acc[1][0] += a.y * b.x; acc[1][1] += a.y * b.y;
    }
    __syncthreads();
  }
  for (int u = 0; u < 2; u++)
    for (int v = 0; v < 2; v++) {
      int i = i0 + ty * 2 + u, j = j0 + tx * 2 + v;
      out[(size_t)i * 256 + j] = 0.5f * acc[u][v];
    }
}

// (Zp0+Zp1)/sqrt(s) * f -> padded buffers. m<2: content -> ncP [b][c][NPS] (k-major);
// m>=2: style -> nsP [b][NP][c] AND nsT [b][c][NPS] (k-major).  grid (36,4,4)
__global__ __launch_bounds__(256) void whiten_pad(
    const float* __restrict__ Zf, const float* __restrict__ scal,
    const float* __restrict__ fc, const float* __restrict__ fs,
    float* __restrict__ ncP, float* __restrict__ nsP, float* __restrict__ nsT) {
  int m = blockIdx.z;
  const float* f = (m < 2) ? (fc + (size_t)m * C_ * N_) : (fs + (size_t)(m - 2) * C_ * N_);
  int c0 = blockIdx.y * 64, x0 = blockIdx.x * 64;
  int t = threadIdx.x;
  int tx = t & 15, ty = t >> 4;
  int sr = t >> 2, skq = t & 3;
  int bkk = t & 15, bc4 = t >> 4;
  __shared__ float sAT[16][68], sB[16][68];
  float acc[4][4] = {};
  for (int k0 = 0; k0 < 256; k0 += 16) {
    size_t ia = (size_t)(c0 + sr) * 256 + k0 + skq * 4;
    float4 a0 = *(const float4*)&Zf[(size_t)m * CC_ + ia];
    float4 a1 = *(const float4*)&Zf[(size_t)(4 + m) * CC_ + ia];
    float4 av = {a0.x + a1.x, a0.y + a1.y, a0.z + a1.z, a0.w + a1.w};
    float4 bv = *(const float4*)&f[(size_t)(k0 + bkk) * N_ + x0 + bc4 * 4];
    __syncthreads();
    sAT[skq * 4 + 0][sr] = av.x; sAT[skq * 4 + 1][sr] = av.y;
    sAT[skq * 4 + 2][sr] = av.z; sAT[skq * 4 + 3][sr] = av.w;
    *(float4*)&sB[bkk][bc4 * 4] = bv;
    __syncthreads();
    GEMM64_COMPUTE(sAT, sB, acc, ty, tx)
  }
  float rs = rsqrtf(scal[m]);
  int b = (m < 2) ? m : (m - 2);
  for (int u = 0; u < 4; u++)
    for (int v = 0; v < 4; v++) {
      int c = c0 + ty * 4 + u, x = x0 + tx * 4 + v;
      int h = x / W_, w = x % W_;
      int pp = (h + 1) * PW_ + (w + 1);
      float val = acc[u][v] * rs;
      if (m < 2) {
        ncP[((size_t)b * C_ + c) * NPS_ + pp] = val;
      } else {
        nsP[((size_t)b * NP_ + pp) * C_ + c] = val;
        nsT[((size_t)b * C_ + c) * NPS_ + pp] = val;
      }
    }
}

// q[b][p] = sum_c nsP[b][p][c]^2
__global__ __launch_bounds__(256) void q_kernel(const float* __restrict__ nsP, float* __restrict__ q) {
  int wid = (blockIdx.x * 256 + threadIdx.x) >> 6;
  int lane = threadIdx.x & 63;
  if (wid >= B_ * NP_) return;
  const float* v = nsP + (size_t)wid * C_;
  float acc = 0.f;
  #pragma unroll
  for (int c = lane; c < C_; c += 64) { float t = v[c]; acc += t * t; }
  acc = waveRed(acc);
  if (lane == 0) q[wid] = acc;
}

// kninv[b][n] = rsqrt( sum over 3x3 of q )
__global__ __launch_bounds__(256) void kninv_kernel(const float* __restrict__ q, float* __restrict__ kninv) {
  int t = blockIdx.x * 256 + threadIdx.x;
  if (t >= B_ * N_) return;
  int b = t / N_, n = t % N_;
  int hn = n / W_, wn = n % W_;
  const float* qb = q + (size_t)b * NP_ + hn * PW_ + wn;
  float s = 0.f;
  #pragma unroll
  for (int i = 0; i < 3; i++)
    #pragma unroll
    for (int j = 0; j < 3; j++) s += qb[i * PW_ + j];
  kninv[t] = rsqrtf(s);
}

// M[i][j] = sum_k At[k][i]*Bt[k][j]; both k-major (stride NPS_), M padded stride MS_.
// Tile 64(i) x 128(j); acc[4][8]; BK=32 single-buffer (44 VGPR, no spill).
// blockIdx.z = batch.
__global__ __launch_bounds__(256) void m_kernel(
    const float* __restrict__ At, const float* __restrict__ Bt, float* __restrict__ M,
    size_t batchA, size_t batchM) {
  size_t bz = blockIdx.z;
  At += bz * batchA; Bt += bz * batchA; M += bz * batchM;
  int i0 = blockIdx.y * 64, j0 = blockIdx.x * 128;
  int t = threadIdx.x;
  int tx = t & 15, ty = t >> 4;
  int ak = t >> 4, ac = t & 15;
  int bk = t >> 5, bc = t & 31;
  __shared__ float sA[32][68], sB[32][132];
  float acc[4][8] = {};
  for (int k0 = 0; k0 < 256; k0 += 32) {
    float4 a0 = *(const float4*)&At[(size_t)(k0 + ak) * NPS_ + i0 + ac * 4];
    float4 a1 = *(const float4*)&At[(size_t)(k0 + ak + 16) * NPS_ + i0 + ac * 4];
    float4 b0 = *(const float4*)&Bt[(size_t)(k0 + bk) * NPS_ + j0 + bc * 4];
    float4 b1 = *(const float4*)&Bt[(size_t)(k0 + bk + 8) * NPS_ + j0 + bc * 4];
    float4 b2 = *(const float4*)&Bt[(size_t)(k0 + bk + 16) * NPS_ + j0 + bc * 4];
    float4 b3 = *(const float4*)&Bt[(size_t)(k0 + bk + 24) * NPS_ + j0 + bc * 4];
    __syncthreads();
    *(float4*)&sA[ak][ac * 4] = a0;
    *(float4*)&sA[ak + 16][ac * 4] = a1;
    *(float4*)&sB[bk][bc * 4] = b0;
    *(float4*)&sB[bk + 8][bc * 4] = b1;
    *(float4*)&sB[bk + 16][bc * 4] = b2;
    *(float4*)&sB[bk + 24][bc * 4] = b3;
    __syncthreads();
    #pragma unroll
    for (int kk = 0; kk < 32; kk++) {
      float4 a  = *(const float4*)&sA[kk][ty * 4];
      float4 p  = *(const float4*)&sB[kk][tx * 4];
      float4 qv = *(const float4*)&sB[kk][64 + tx * 4];
      acc[0][0] += a.x * p.x; acc[0][1] += a.x * p.y; acc[0][2] += a.x * p.z; acc[0][3] += a.x * p.w;
      acc[1][0] += a.y * p.x; acc[1][1] += a.y * p.y; acc[1][2] += a.y * p.z; acc[1][3] += a.y * p.w;
      acc[2][0] += a.z * p.x; acc[2][1] += a.z * p.y; acc[2][2] += a.z * p.z; acc[2][3] += a.z * p.w;
      acc[3][0] += a.w * p.x; acc[3][1] += a.w * p.y; acc[3][2] += a.w * p.z; acc[3][3] += a.w * p.w;
      acc[0][4] += a.x * qv.x; acc[0][5] += a.x * qv.y; acc[0][6] += a.x * qv.z; acc[0][7] += a.x * qv.w;
      acc[1][4] += a.y * qv.x; acc[1][5] += a.y * qv.y; acc[1][6] += a.y * qv.z; acc[1][7] += a.y * qv.w;
      acc[2][4] += a.z * qv.x; acc[2][5] += a.z * qv.y; acc[2][6] += a.z * qv.z; acc[2][7] += a.z * qv.w;
      acc[3][4] += a.w * qv.x; acc[3][5] += a.w * qv.y; acc[3][6] += a.w * qv.z; acc[3][7] += a.w * qv.w;
    }
    __syncthreads();
  }
  #pragma unroll
  for (int u = 0; u < 4; u++) {
    size_t row = (size_t)(i0 + ty * 4 + u) * MS_;
    float4 s0 = {acc[u][0], acc[u][1], acc[u][2], acc[u][3]};
    float4 s1 = {acc[u][4], acc[u][5], acc[u][6], acc[u][7]};
    *(float4*)&M[row + j0 + tx * 4] = s0;
    *(float4*)&M[row + j0 + 64 + tx * 4] = s1;
  }
}

// Partial argmax over an n-chunk for each content position m. (M stride MS_)
// batch = b0 + blockIdx.z; M offset by blockIdx.z * batchM.
__global__ __launch_bounds__(256) void score_kernel(
    const float* __restrict__ M, const float* __restrict__ kninv,
    float* __restrict__ pval, int* __restrict__ pidx, int b0, size_t batchM) {
  int b = b0 + blockIdx.z;
  M += (size_t)blockIdx.z * batchM;
  int m = blockIdx.x * 256 + threadIdx.x;
  int h = m / W_, w = m % W_;
  int cm = h * PW_ + w;
  int n0 = blockIdx.y * NC_;
  const float* kni = kninv + (size_t)b * N_;
  float best = -3.4e38f;
  int bidx = n0;
  for (int n = n0; n < n0 + NC_; n++) {
    int hn = n / W_, wn = n % W_;
    int rn = hn * PW_ + wn;
    const float* base = M + (size_t)rn * MS_ + cm;
    float s = 0.f;
    #pragma unroll
    for (int i = 0; i < 3; i++)
      #pragma unroll
      for (int j = 0; j < 3; j++) s += base[(size_t)(i * PW_ + j) * (MS_ + 1)];
    s *= kni[n];
    if (s > best) { best = s; bidx = n; }
  }
  pval[((size_t)b * NCH_ + blockIdx.y) * N_ + m] = best;
  pidx[((size_t)b * NCH_ + blockIdx.y) * N_ + m] = bidx;
}

// Final argmax across chunks (ascending => first-max wins, matches jnp.argmax)
__global__ __launch_bounds__(256) void argmax_final(
    const float* __restrict__ pval, const int* __restrict__ pidx, int* __restrict__ idxb) {
  int t = blockIdx.x * 256 + threadIdx.x;
  if (t >= B_ * N_) return;
  int b = t / N_, m = t % N_;
  float best = -3.4e38f; int bidx = 0;
  for (int ch = 0; ch < NCH_; ch++) {
    float v = pval[((size_t)b * NCH_ + ch) * N_ + m];
    int i = pidx[((size_t)b * NCH_ + ch) * N_ + m];
    if (v > best) { best = v; bidx = i; }
  }
  idxb[t] = bidx;
}

// Overlap-add reassembly: recon[b][m][c] (position-major).
// One WAVE per position; lanes cover channels as float4. grid = B*N/4 blocks.
__global__ __launch_bounds__(256) void reassemble_kernel(
    const float* __restrict__ nsP, const int* __restrict__ idxb, float* __restrict__ recon) {
  int t = threadIdx.x;
  int sub = t >> 6, lane = t & 63;
  int p = blockIdx.x * 4 + sub;          // global (b,m) index
  int b = p / N_, m = p % N_;
  int h = m / W_, w = m % W_;
  float4 acc = {0.f, 0.f, 0.f, 0.f};
  int cnt = 0;
  for (int di = 0; di < 3; di++) {
    int hs = h + 1 - di; if (hs < 0 || hs >= H_) continue;
    for (int dj = 0; dj < 3; dj++) {
      int ws = w + 1 - dj; if (ws < 0 || ws >= W_) continue;
      int n = idxb[(size_t)b * N_ + hs * W_ + ws];
      int hn = n / W_, wn = n % W_;
      int pp = (hn + di) * PW_ + (wn + dj);
      float4 v = *(const float4*)&nsP[((size_t)b * NP_ + pp) * C_ + lane * 4];
      acc.x += v.x; acc.y += v.y; acc.z += v.z; acc.w += v.w;
      cnt++;
    }
  }
  float inv = 1.0f / (float)cnt;
  acc.x *= inv; acc.y *= inv; acc.z *= inv; acc.w *= inv;
  *(float4*)&recon[((size_t)b * N_ + m) * C_ + lane * 4] = acc;
}

// Partial column sums of recon over x-chunks
__global__ __launch_bounds__(256) void rmean_part(const float* __restrict__ recon, float* __restrict__ pmr) {
  int b = blockIdx.y, ch = blockIdx.x, c = threadIdx.x;
  float acc = 0.f;
  int x0 = ch * (N_ / 16);
  for (int x = x0; x < x0 + (N_ / 16); x++) acc += recon[((size_t)b * N_ + x) * C_ + c];
  pmr[((size_t)b * 16 + ch) * C_ + c] = acc;
}

__global__ __launch_bounds__(256) void rmean_fin(const float* __restrict__ pmr, float* __restrict__ mr) {
  int b = blockIdx.x, c = threadIdx.x;
  float acc = 0.f;
  for (int ch = 0; ch < 16; ch++) acc += pmr[((size_t)b * 16 + ch) * C_ + c];
  mr[(size_t)b * C_ + c] = acc * (1.0f / N_);
}

// stylized = sqrt(cov_s)*(recon-mr) + mean_s ; out = (1-ss)*content + ss*stylized
// grid (36,4,2). A = (Yp0+Yp1) (style matrix m=2+b)
__global__ __launch_bounds__(256) void color_blend(
    const float* __restrict__ Yf, const float* __restrict__ scal,
    const float* __restrict__ recon, const float* __restrict__ mr,
    const float* __restrict__ msty, const float* __restrict__ content,
    const float* __restrict__ ssp, float* __restrict__ out) {
  int b = blockIdx.z;
  int m = 2 + b;
  int c0 = blockIdx.y * 64, x0 = blockIdx.x * 64;
  int t = threadIdx.x;
  int tx = t & 15, ty = t >> 4;
  int sr = t >> 2, skq = t & 3;
  __shared__ float sAT[16][68], sB[16][68];
  float acc[4][4] = {};
  for (int k0 = 0; k0 < 256; k0 += 16) {
    size_t ia = (size_t)(c0 + sr) * 256 + k0 + skq * 4;
    float4 a0 = *(const float4*)&Yf[(size_t)m * CC_ + ia];
    float4 a1 = *(const float4*)&Yf[(size_t)(4 + m) * CC_ + ia];
    float4 av = {a0.x + a1.x, a0.y + a1.y, a0.z + a1.z, a0.w + a1.w};
    float4 bm4 = *(const float4*)&mr[(size_t)b * C_ + k0 + skq * 4];
    float4 bv = *(const float4*)&recon[((size_t)b * N_ + x0 + sr) * C_ + k0 + skq * 4];
    bv.x -= bm4.x; bv.y -= bm4.y; bv.z -= bm4.z; bv.w -= bm4.w;
    __syncthreads();
    sAT[skq * 4 + 0][sr] = av.x; sAT[skq * 4 + 1][sr] = av.y;
    sAT[skq * 4 + 2][sr] = av.z; sAT[skq * 4 + 3][sr] = av.w;
    sB[skq * 4 + 0][sr] = bv.x;  sB[skq * 4 + 1][sr] = bv.y;
    sB[skq * 4 + 2][sr] = bv.z;  sB[skq * 4 + 3][sr] = bv.w;
    __syncthreads();
    GEMM64_COMPUTE(sAT, sB, acc, ty, tx)
  }
  float sq = sqrtf(scal[m]);
  float ss = ssp[0];
  for (int u = 0; u < 4; u++)
    for (int v = 0; v < 4; v++) {
      int c = c0 + ty * 4 + u, x = x0 + tx * 4 + v;
      float sty = acc[u][v] * sq + msty[(size_t)b * C_ + c];
      size_t o = ((size_t)b * C_ + c) * N_ + x;
      out[o] = (1.0f - ss) * content[o] + ss * sty;
    }
}

// ---------------- host launch ----------------
extern "C" void kernel_launch(void* const* d_in, const int* in_sizes, int n_in,
                              void* d_out, int out_size, void* d_ws, size_t ws_size,
                              hipStream_t stream) {
  (void)in_sizes; (void)n_in; (void)out_size;
  const float* content = (const float*)d_in[0];
  const float* style   = (const float*)d_in[1];
  const float* ssp     = (const float*)d_in[2];
  float* out = (float*)d_out;
  float* W = (float*)d_ws;

  // workspace layout (floats)
  size_t off = 0;
  float* fc   = W + off; off += (size_t)B_ * C_ * N_;
  float* fs   = W + off; off += (size_t)B_ * C_ * N_;   // recon aliases fs later
  float* nsP  = W + off; off += (size_t)B_ * NP_ * C_;
  float* nsT  = W + off; off += (size_t)B_ * C_ * NPS_;
  float* ncP  = W + off; off += (size_t)B_ * C_ * NPS_;
  float* Ya   = W + off; off += (size_t)8 * CC_;   // 2-partial sets
  float* Yb   = W + off; off += (size_t)8 * CC_;
  float* Za   = W + off; off += (size_t)8 * CC_;
  float* Zb   = W + off; off += (size_t)8 * CC_;
  float* scal = W + off; off += 4;
  float* msty = W + off; off += (size_t)B_ * C_;
  float* mr   = W + off; off += (size_t)B_ * C_;
  float* pmr  = W + off; off += (size_t)B_ * 16 * C_;
  float* q    = W + off; off += (size_t)B_ * NP_;
  float* kni  = W + off; off += (size_t)B_ * N_;
  float* pval = W + off; off += (size_t)B_ * NCH_ * N_;
  float* Mb   = W + off;
  size_t off_Mb = off;

  size_t off1 = off_Mb + (size_t)MS_ * MS_;        // single-M layout
  size_t off2 = off_Mb + (size_t)2 * MS_ * MS_;    // dual-M layout
  size_t tail = (size_t)B_ * NCH_ * N_ + (size_t)B_ * N_;   // pidx + idxb
  bool dual = ws_size >= (off2 + tail) * sizeof(float);
  size_t offM = dual ? off2 : off1;
  int* pidx = (int*)(W + offM);
  int* idxb = (int*)(W + offM + (size_t)B_ * NCH_ * N_);
  float* pcov = Mb;          // 9*4*CC = 2.36M floats (dead before m_kernel)
  float* T    = Mb + (size_t)KCH_ * 4 * CC_;  // 8*CC floats; lives after pcov (pcov still
                                              // read by ns_init; disjoint region of Mb)
  float* recon = fs;         // fs dead after whiten_pad

  border_zero<<<904, 256, 0, stream>>>(nsP, nsT, ncP);

  center_kernel<<<2 * B_ * C_, 256, 0, stream>>>(content, style, fc, fs, msty);
  cov_kernel<<<dim3(4, 4, 4 * KCH_), 256, 0, stream>>>(fc, fs, pcov);
  ns_init<<<dim3(16, 4), 256, 0, stream>>>(pcov, Ya, Za, scal);

  float *Ycur = Ya, *Zcur = Za, *Yalt = Yb, *Zalt = Zb;
  for (int it = 0; it < NSIT_; it++) {
    ns_stepA<<<dim3(8, 8, 8), 256, 0, stream>>>(Zcur, Ycur, T);
    ns_stepB<<<dim3(8, 8, 16), 256, 0, stream>>>(Ycur, Zcur, T, Yalt, Zalt);
    float* tp;
    tp = Ycur; Ycur = Yalt; Yalt = tp;
    tp = Zcur; Zcur = Zalt; Zalt = tp;
  }

  whiten_pad<<<dim3(36, 4, 4), 256, 0, stream>>>(Zcur, scal, fc, fs, ncP, nsP, nsT);
  q_kernel<<<(B_ * NP_ + 3) / 4, 256, 0, stream>>>(nsP, q);
  kninv_kernel<<<(B_ * N_ + 255) / 256, 256, 0, stream>>>(q, kni);

  if (dual) {
    m_kernel<<<dim3(20, 40, 2), 256, 0, stream>>>(
        nsT, ncP, Mb, (size_t)C_ * NPS_, (size_t)MS_ * MS_);
    score_kernel<<<dim3(N_ / 256, NCH_, 2), 256, 0, stream>>>(
        Mb, kni, pval, pidx, 0, (size_t)MS_ * MS_);
  } else {
    for (int b = 0; b < B_; b++) {
      m_kernel<<<dim3(20, 40, 1), 256, 0, stream>>>(
          nsT + (size_t)b * C_ * NPS_, ncP + (size_t)b * C_ * NPS_, Mb, 0, 0);
      score_kernel<<<dim3(N_ / 256, NCH_, 1), 256, 0, stream>>>(
          Mb, kni, pval, pidx, b, 0);
    }
  }
  argmax_final<<<(B_ * N_ + 255) / 256, 256, 0, stream>>>(pval, pidx, idxb);
  reassemble_kernel<<<B_ * N_ / 4, 256, 0, stream>>>(nsP, idxb, recon);
  rmean_part<<<dim3(16, B_), 256, 0, stream>>>(recon, pmr);
  rmean_fin<<<B_, 256, 0, stream>>>(pmr, mr);
  color_blend<<<dim3(36, 4, B_), 256, 0, stream>>>(
      Ycur, scal, recon, mr, msty, content, ssp, out);
}